// Round 5
// baseline (105.712 us; speedup 1.0000x reference)
//
#include <hip/hip_runtime.h>
#include <hip/hip_bf16.h>
#include <stdint.h>

typedef __attribute__((ext_vector_type(8))) short short8;
typedef __attribute__((ext_vector_type(4))) float f32x4;

#define N_PTS 8192
#define M_PTS 8192
#define DIM   512
#define KDIM  128
#define BT    128   // phi_b tile
#define BKS   32
#define BM    256   // gemm tile
#define BN    256
#define BKQ   32

// ---- float <-> order-preserving uint key (for atomicMin on float) ----
__device__ __forceinline__ unsigned fenc(float f) {
  unsigned u = __float_as_uint(f);
  return (u & 0x80000000u) ? ~u : (u | 0x80000000u);
}
__device__ __forceinline__ float fdec(unsigned k) {
  unsigned u = (k & 0x80000000u) ? (k ^ 0x80000000u) : ~k;
  return __uint_as_float(u);
}

__device__ __forceinline__ unsigned short f2bf(float f) {
  union { __hip_bfloat16 h; unsigned short u; } c;
  c.h = __float2bfloat16(f);
  return c.u;
}

// ---- async global -> LDS, 16B per lane ----
__device__ __forceinline__ void async_copy16(const void* g, void* l) {
  __builtin_amdgcn_global_load_lds(
      (const __attribute__((address_space(1))) void*)g,
      (__attribute__((address_space(3))) void*)l, 16, 0, 0);
}

// ---- LDS slot swizzle (verified: conflicts -> 0): 4 slots of 16B/row ----
__device__ __forceinline__ int swz_slot(int row, int slot) {
  return slot ^ ((row >> 1) & 3);
}

// =====================================================================
// Kernel 1: streaming cast x & target -> bf16, row sumsq, key init.
// =====================================================================
__global__ __launch_bounds__(256)
void cast_rows_kernel(const float* __restrict__ x, const float* __restrict__ tgt,
                      unsigned short* __restrict__ Xb, unsigned short* __restrict__ Tb,
                      float* __restrict__ xsq, float* __restrict__ tsq,
                      unsigned* __restrict__ keys) {
  const int gw = (blockIdx.x * 256 + threadIdx.x) >> 6;
  const int lane = threadIdx.x & 63;
  const float* src;
  unsigned short* dst;
  float* sq;
  int trow = -1;
  if (gw < N_PTS) {
    src = x + (size_t)gw * DIM;
    dst = Xb + (size_t)gw * DIM;
    sq = xsq + gw;
  } else {
    trow = gw - N_PTS;
    src = tgt + (size_t)trow * DIM;
    dst = Tb + (size_t)trow * DIM;
    sq = tsq + trow;
  }
  float s = 0.f;
#pragma unroll
  for (int i = 0; i < 2; ++i) {
    float4 v = ((const float4*)src)[i * 64 + lane];
    s += v.x * v.x + v.y * v.y + v.z * v.z + v.w * v.w;
    ushort4 o;
    o.x = f2bf(v.x); o.y = f2bf(v.y); o.z = f2bf(v.z); o.w = f2bf(v.w);
    ((ushort4*)dst)[i * 64 + lane] = o;
  }
#pragma unroll
  for (int m = 1; m <= 32; m <<= 1) s += __shfl_xor(s, m);
  if (lane == 0) {
    *sq = s;
    if (trow >= 0) keys[trow] = 0xFFFFFFFFu;
  }
}

// =====================================================================
// Kernel 2: W [D][K] fp32 -> WbT [K][D] bf16 (transposed cast)
// =====================================================================
__global__ __launch_bounds__(256)
void prep_w_kernel(const float* __restrict__ W, unsigned short* __restrict__ WbT) {
  const int o = blockIdx.x * 256 + threadIdx.x;
  const int k = o >> 9, d = o & 511;
  WbT[o] = f2bf(W[d * KDIM + k]);
}

// =====================================================================
// Kernel 3: phi_b = logsumexp(Xb @ WbT^T) via MFMA + in-LDS logsumexp.
// =====================================================================
__global__ __launch_bounds__(256)
void phi_b_kernel(const short* __restrict__ Xb, const short* __restrict__ WbT,
                  float* __restrict__ phi_b) {
  __shared__ __align__(16) short As[BT * BKS];
  __shared__ __align__(16) short Bs[BT * BKS];
  __shared__ __align__(16) float lg[128][136];

  const int tid = threadIdx.x;
  const int wave = tid >> 6, lane = tid & 63;
  const int n0 = blockIdx.x * BT;
  const int srow = tid >> 2;
  const int sk8 = swz_slot(srow, tid & 3) * 8;
  const int wr = wave >> 1, wc = wave & 1;
  const int fr = lane & 15, g = lane >> 4;

  f32x4 acc[4][4] = {};
  for (int kt = 0; kt < DIM / BKS; ++kt) {
    const int k0 = kt * BKS;
    async_copy16(Xb + (size_t)(n0 + srow) * DIM + k0 + sk8, &As[wave * 512]);
    async_copy16(Xb + (size_t)(n0 + srow + 64) * DIM + k0 + sk8, &As[2048 + wave * 512]);
    async_copy16(WbT + (size_t)srow * DIM + k0 + sk8, &Bs[wave * 512]);
    async_copy16(WbT + (size_t)(srow + 64) * DIM + k0 + sk8, &Bs[2048 + wave * 512]);
    __syncthreads();
    short8 a[4], b[4];
#pragma unroll
    for (int i = 0; i < 4; ++i) {
      const int R = wr * 64 + i * 16 + fr;
      a[i] = *(const short8*)&As[R * BKS + swz_slot(R, g) * 8];
    }
#pragma unroll
    for (int j = 0; j < 4; ++j) {
      const int R = wc * 64 + j * 16 + fr;
      b[j] = *(const short8*)&Bs[R * BKS + swz_slot(R, g) * 8];
    }
#pragma unroll
    for (int i = 0; i < 4; ++i)
#pragma unroll
      for (int j = 0; j < 4; ++j)
        acc[i][j] = __builtin_amdgcn_mfma_f32_16x16x32_bf16(a[i], b[j], acc[i][j], 0, 0, 0);
    __syncthreads();
  }

  const int rq = g * 4;
#pragma unroll
  for (int i = 0; i < 4; ++i)
#pragma unroll
    for (int j = 0; j < 4; ++j)
#pragma unroll
      for (int q = 0; q < 4; ++q)
        lg[wr * 64 + i * 16 + rq + q][wc * 64 + j * 16 + fr] = acc[i][j][q];
  __syncthreads();

  const int row = tid >> 1, half = tid & 1;
  const float4* lr = (const float4*)(&lg[row][half * 64]);
  float mx = -3.4e38f;
#pragma unroll
  for (int c = 0; c < 16; ++c) {
    float4 v = lr[c];
    mx = fmaxf(mx, fmaxf(fmaxf(v.x, v.y), fmaxf(v.z, v.w)));
  }
  mx = fmaxf(mx, __shfl_xor(mx, 1));
  float s = 0.f;
#pragma unroll
  for (int c = 0; c < 16; ++c) {
    float4 v = lr[c];
    s += __expf(v.x - mx) + __expf(v.y - mx) + __expf(v.z - mx) + __expf(v.w - mx);
  }
  s += __shfl_xor(s, 1);
  if (half == 0) phi_b[n0 + row] = mx + logf(s);
}

// =====================================================================
// Kernel 4: fused bf16 MFMA GEMM (x @ target^T) + min_n(phi_b[n]-dot)
// 256x256 tile, BK=32, 8 waves (2Mx4N), 4 LDS buffers, 3-deep prefetch.
// SW-pipelined fragment reads: phase p issues reads for phase p+1, so
// the LDS pipe services reads DURING the MFMA cluster; consumers rely
// on compiler-counted lgkmcnt(4/8). vmcnt(6) steady state (never 0).
// =====================================================================
__device__ __forceinline__ void stage_A(const short* __restrict__ Xb, short* Abuf,
                                        int n0, int k0, int tid) {
  const int row = tid >> 2;
  const int sw8 = ((tid & 3) ^ ((row >> 1) & 3)) * 8;
  const int wvb = (tid >> 6) * 512;
  async_copy16(Xb + (size_t)(n0 + row) * DIM + k0 + sw8, Abuf + wvb);
  async_copy16(Xb + (size_t)(n0 + 128 + row) * DIM + k0 + sw8, Abuf + 4096 + wvb);
}
__device__ __forceinline__ void stage_B(const short* __restrict__ Tb, short* Bbuf,
                                        int m0, int k0, int tid) {
  const int row = tid >> 2;
  const int sw8 = ((tid & 3) ^ ((row >> 1) & 3)) * 8;
  const int wvb = (tid >> 6) * 512;
  async_copy16(Tb + (size_t)(m0 + row) * DIM + k0 + sw8, Bbuf + wvb);
  async_copy16(Tb + (size_t)(m0 + 128 + row) * DIM + k0 + sw8, Bbuf + 4096 + wvb);
}

// STG: stage tile t+3.  VMC: vmcnt value for this tile (-1 = none).
// PRE: pre-read next tile's P0 fragments during P1.
template <bool STG, int VMC, bool PRE>
__device__ __forceinline__ void tile_body(const short* __restrict__ Ab,
                                          const short* __restrict__ Bb,
                                          const short* __restrict__ Abn,
                                          const short* __restrict__ Bbn,
                                          short* Asg, short* Bsg,
                                          const short* __restrict__ Xb,
                                          const short* __restrict__ Tb,
                                          int n0, int m0, int k3, int tid,
                                          int aoff0, int boff0,
                                          short8 (&a_cur)[4], short8 (&b_cur)[4],
                                          f32x4 (&acc)[8][4]) {
  // ---- phase 0: issue reads for this tile's P1 (rows 4-7); MFMA rows 0-3
  short8 a_nxt[4];
#pragma unroll
  for (int i = 0; i < 4; ++i) a_nxt[i] = *(const short8*)(Ab + aoff0 + (4 + i) * 512);
  if (STG) stage_A(Xb, Asg, n0, k3, tid);
  if (VMC == 6) asm volatile("s_waitcnt vmcnt(6)" ::: "memory");
  else if (VMC == 4) asm volatile("s_waitcnt vmcnt(4)" ::: "memory");
  else if (VMC == 0) asm volatile("s_waitcnt vmcnt(0)" ::: "memory");
  __builtin_amdgcn_s_barrier();
  __builtin_amdgcn_s_setprio(1);
#pragma unroll
  for (int i = 0; i < 4; ++i)
#pragma unroll
    for (int j = 0; j < 4; ++j)
      acc[i][j] = __builtin_amdgcn_mfma_f32_16x16x32_bf16(a_cur[i], b_cur[j], acc[i][j], 0, 0, 0);
  __builtin_amdgcn_s_setprio(0);
  __builtin_amdgcn_s_barrier();
  // ---- phase 1: issue reads for NEXT tile's P0; MFMA rows 4-7
  short8 a_pre[4], b_pre[4];
  if (PRE) {
#pragma unroll
    for (int i = 0; i < 4; ++i) a_pre[i] = *(const short8*)(Abn + aoff0 + i * 512);
#pragma unroll
    for (int j = 0; j < 4; ++j) b_pre[j] = *(const short8*)(Bbn + boff0 + j * 512);
  }
  if (STG) stage_B(Tb, Bsg, m0, k3, tid);
  __builtin_amdgcn_s_barrier();
  __builtin_amdgcn_s_setprio(1);
#pragma unroll
  for (int i = 0; i < 4; ++i)
#pragma unroll
    for (int j = 0; j < 4; ++j)
      acc[4 + i][j] = __builtin_amdgcn_mfma_f32_16x16x32_bf16(a_nxt[i], b_cur[j], acc[4 + i][j], 0, 0, 0);
  __builtin_amdgcn_s_setprio(0);
  __builtin_amdgcn_s_barrier();
  if (PRE) {
#pragma unroll
    for (int i = 0; i < 4; ++i) a_cur[i] = a_pre[i];
#pragma unroll
    for (int j = 0; j < 4; ++j) b_cur[j] = b_pre[j];
  }
}

__global__ __launch_bounds__(512, 2)
void gemm_min_kernel(const short* __restrict__ Xb, const short* __restrict__ Tb,
                     const float* __restrict__ phi_b, unsigned* __restrict__ keys) {
  __shared__ __align__(16) short As[4][BM * BKQ];   // 4 x 16 KB
  __shared__ __align__(16) short Bs[4][BN * BKQ];   // 4 x 16 KB (128 KiB)

  const int tid = threadIdx.x;
  const int wave = tid >> 6, lane = tid & 63;
  const int wm = wave >> 2, wn = wave & 3;
  const int fr = lane & 15, g = lane >> 4;
  const int n0 = blockIdx.y * BM;
  const int m0 = blockIdx.x * BN;

  const int key8 = (g ^ ((fr >> 1) & 3)) * 8;
  const int aoff0 = (wm * 128 + fr) * BKQ + key8;
  const int boff0 = (wn * 64 + fr) * BKQ + key8;

  f32x4 acc[8][4] = {};

  // prologue: stage tiles 0,1,2; retire tile 0; read tile-0 P0 fragments
  stage_A(Xb, As[0], n0, 0, tid);        stage_B(Tb, Bs[0], m0, 0, tid);
  stage_A(Xb, As[1], n0, BKQ, tid);      stage_B(Tb, Bs[1], m0, BKQ, tid);
  stage_A(Xb, As[2], n0, 2 * BKQ, tid);  stage_B(Tb, Bs[2], m0, 2 * BKQ, tid);
  asm volatile("s_waitcnt vmcnt(8)" ::: "memory");
  __builtin_amdgcn_s_barrier();
  short8 a_cur[4], b_cur[4];
#pragma unroll
  for (int i = 0; i < 4; ++i) a_cur[i] = *(const short8*)(As[0] + aoff0 + i * 512);
#pragma unroll
  for (int j = 0; j < 4; ++j) b_cur[j] = *(const short8*)(Bs[0] + boff0 + j * 512);

#pragma unroll 1
  for (int t = 0; t < 13; ++t) {
    tile_body<true, 6, true>(As[t & 3], Bs[t & 3], As[(t + 1) & 3], Bs[(t + 1) & 3],
                             As[(t + 3) & 3], Bs[(t + 3) & 3],
                             Xb, Tb, n0, m0, (t + 3) * BKQ, tid, aoff0, boff0,
                             a_cur, b_cur, acc);
  }
  tile_body<false, 4, true>(As[1], Bs[1], As[2], Bs[2], As[0], Bs[0],
                            Xb, Tb, n0, m0, 0, tid, aoff0, boff0, a_cur, b_cur, acc);
  tile_body<false, 0, true>(As[2], Bs[2], As[3], Bs[3], As[0], Bs[0],
                            Xb, Tb, n0, m0, 0, tid, aoff0, boff0, a_cur, b_cur, acc);
  tile_body<false, -1, false>(As[3], Bs[3], As[0], Bs[0], As[0], Bs[0],
                              Xb, Tb, n0, m0, 0, tid, aoff0, boff0, a_cur, b_cur, acc);

  // Epilogue: v = phi_b[n] - dot(n,m); per-column min over wave's 128 rows.
  const int rq = g * 4;
  float mv[4] = {3.4e38f, 3.4e38f, 3.4e38f, 3.4e38f};
#pragma unroll
  for (int i = 0; i < 8; ++i) {
    float pb[4];
#pragma unroll
    for (int q = 0; q < 4; ++q) pb[q] = phi_b[n0 + wm * 128 + i * 16 + rq + q];
#pragma unroll
    for (int j = 0; j < 4; ++j)
#pragma unroll
      for (int q = 0; q < 4; ++q) mv[j] = fminf(mv[j], pb[q] - acc[i][j][q]);
  }
#pragma unroll
  for (int j = 0; j < 4; ++j) {
    float v = mv[j];
    v = fminf(v, __shfl_xor(v, 16));
    v = fminf(v, __shfl_xor(v, 32));
    if (g == 0) {
      atomicMin(&keys[m0 + wn * 64 + j * 16 + fr], fenc(v));
    }
  }
}

// =====================================================================
// Kernel 5: final reduce: mean(phi_k) + mean(phi_c). 1 block, 1024 thr.
// =====================================================================
__global__ __launch_bounds__(1024)
void finalize_kernel(const float* __restrict__ xsq, const float* __restrict__ phi_b,
                     const float* __restrict__ tsq, const unsigned* __restrict__ keys,
                     float* __restrict__ out) {
  const int t = threadIdx.x;
  double sk = 0.0, sc = 0.0;
  for (int n = t; n < N_PTS; n += 1024) sk += 0.5 * (double)xsq[n] - (double)phi_b[n];
  for (int m = t; m < M_PTS; m += 1024) sc += 0.5 * (double)tsq[m] + (double)fdec(keys[m]);
  const int lane = t & 63, wv = t >> 6;
#pragma unroll
  for (int m = 1; m <= 32; m <<= 1) {
    sk += __shfl_xor(sk, m);
    sc += __shfl_xor(sc, m);
  }
  __shared__ double pk[16], pc[16];
  if (lane == 0) { pk[wv] = sk; pc[wv] = sc; }
  __syncthreads();
  if (t == 0) {
    double a = 0.0, c = 0.0;
#pragma unroll
    for (int i = 0; i < 16; ++i) { a += pk[i]; c += pc[i]; }
    out[0] = (float)(a / N_PTS + c / M_PTS);
  }
}

// =====================================================================
extern "C" void kernel_launch(void* const* d_in, const int* in_sizes, int n_in,
                              void* d_out, int out_size, void* d_ws, size_t ws_size,
                              hipStream_t stream) {
  const float* x = (const float*)d_in[0];
  const float* tgt = (const float*)d_in[1];
  const float* W = (const float*)d_in[2];

  char* ws = (char*)d_ws;
  const size_t XB_BYTES = (size_t)N_PTS * DIM * 2;
  const size_t TB_BYTES = (size_t)M_PTS * DIM * 2;
  const size_t WT_BYTES = (size_t)KDIM * DIM * 2;
  unsigned short* Xb = (unsigned short*)ws;
  unsigned short* Tb = (unsigned short*)(ws + XB_BYTES);
  unsigned short* WbT = (unsigned short*)(ws + XB_BYTES + TB_BYTES);
  float* phi_b = (float*)(ws + XB_BYTES + TB_BYTES + WT_BYTES);
  float* xsq = phi_b + N_PTS;
  float* tsq = xsq + N_PTS;
  unsigned* keys = (unsigned*)(tsq + M_PTS);

  cast_rows_kernel<<<(N_PTS + M_PTS) / 4, 256, 0, stream>>>(x, tgt, Xb, Tb, xsq, tsq, keys);
  prep_w_kernel<<<(KDIM * DIM) / 256, 256, 0, stream>>>(W, WbT);
  phi_b_kernel<<<N_PTS / BT, 256, 0, stream>>>((const short*)Xb, (const short*)WbT, phi_b);
  gemm_min_kernel<<<dim3(M_PTS / BN, N_PTS / BM), 512, 0, stream>>>(
      (const short*)Xb, (const short*)Tb, phi_b, keys);
  finalize_kernel<<<1, 1024, 0, stream>>>(xsq, phi_b, tsq, keys, (float*)d_out);
}

// Round 6
// 103.350 us; speedup vs baseline: 1.0229x; 1.0229x over previous
//
#include <hip/hip_runtime.h>
#include <hip/hip_bf16.h>
#include <stdint.h>

typedef __attribute__((ext_vector_type(8))) short short8;
typedef __attribute__((ext_vector_type(4))) float f32x4;

#define N_PTS 8192
#define M_PTS 8192
#define DIM   512
#define KDIM  128
#define BT    128   // phi_b tile
#define BKS   32
#define BM    256   // gemm tile
#define BN    256

// gemm LDS region offsets (elements): per buffer A[2][256][32] then B[2][256][32]
#define BREG  16384
#define KS1   8192

// ---- float <-> order-preserving uint key (for atomicMin on float) ----
__device__ __forceinline__ unsigned fenc(float f) {
  unsigned u = __float_as_uint(f);
  return (u & 0x80000000u) ? ~u : (u | 0x80000000u);
}
__device__ __forceinline__ float fdec(unsigned k) {
  unsigned u = (k & 0x80000000u) ? (k ^ 0x80000000u) : ~k;
  return __uint_as_float(u);
}

__device__ __forceinline__ unsigned short f2bf(float f) {
  union { __hip_bfloat16 h; unsigned short u; } c;
  c.h = __float2bfloat16(f);
  return c.u;
}

// ---- async global -> LDS, 16B per lane ----
__device__ __forceinline__ void async_copy16(const void* g, void* l) {
  __builtin_amdgcn_global_load_lds(
      (const __attribute__((address_space(1))) void*)g,
      (__attribute__((address_space(3))) void*)l, 16, 0, 0);
}

// ---- LDS slot swizzle (verified: conflicts -> 0): 4 slots of 16B per 64B row
__device__ __forceinline__ int swz_slot(int row, int slot) {
  return slot ^ ((row >> 1) & 3);
}

// =====================================================================
// Kernel 1: streaming cast x & target -> bf16, row sumsq, key init.
// =====================================================================
__global__ __launch_bounds__(256)
void cast_rows_kernel(const float* __restrict__ x, const float* __restrict__ tgt,
                      unsigned short* __restrict__ Xb, unsigned short* __restrict__ Tb,
                      float* __restrict__ xsq, float* __restrict__ tsq,
                      unsigned* __restrict__ keys) {
  const int gw = (blockIdx.x * 256 + threadIdx.x) >> 6;
  const int lane = threadIdx.x & 63;
  const float* src;
  unsigned short* dst;
  float* sq;
  int trow = -1;
  if (gw < N_PTS) {
    src = x + (size_t)gw * DIM;
    dst = Xb + (size_t)gw * DIM;
    sq = xsq + gw;
  } else {
    trow = gw - N_PTS;
    src = tgt + (size_t)trow * DIM;
    dst = Tb + (size_t)trow * DIM;
    sq = tsq + trow;
  }
  float s = 0.f;
#pragma unroll
  for (int i = 0; i < 2; ++i) {
    float4 v = ((const float4*)src)[i * 64 + lane];
    s += v.x * v.x + v.y * v.y + v.z * v.z + v.w * v.w;
    ushort4 o;
    o.x = f2bf(v.x); o.y = f2bf(v.y); o.z = f2bf(v.z); o.w = f2bf(v.w);
    ((ushort4*)dst)[i * 64 + lane] = o;
  }
#pragma unroll
  for (int m = 1; m <= 32; m <<= 1) s += __shfl_xor(s, m);
  if (lane == 0) {
    *sq = s;
    if (trow >= 0) keys[trow] = 0xFFFFFFFFu;
  }
}

// =====================================================================
// Kernel 2: W [D][K] fp32 -> WbT [K][D] bf16 (transposed cast)
// =====================================================================
__global__ __launch_bounds__(256)
void prep_w_kernel(const float* __restrict__ W, unsigned short* __restrict__ WbT) {
  const int o = blockIdx.x * 256 + threadIdx.x;
  const int k = o >> 9, d = o & 511;
  WbT[o] = f2bf(W[d * KDIM + k]);
}

// =====================================================================
// Kernel 3: phi_b = logsumexp(Xb @ WbT^T) via MFMA + in-LDS logsumexp.
// =====================================================================
__global__ __launch_bounds__(256)
void phi_b_kernel(const short* __restrict__ Xb, const short* __restrict__ WbT,
                  float* __restrict__ phi_b) {
  __shared__ __align__(16) short As[BT * BKS];
  __shared__ __align__(16) short Bs[BT * BKS];
  __shared__ __align__(16) float lg[128][136];

  const int tid = threadIdx.x;
  const int wave = tid >> 6, lane = tid & 63;
  const int n0 = blockIdx.x * BT;
  const int srow = tid >> 2;
  const int sk8 = swz_slot(srow, tid & 3) * 8;
  const int wr = wave >> 1, wc = wave & 1;
  const int fr = lane & 15, g = lane >> 4;

  f32x4 acc[4][4] = {};
  for (int kt = 0; kt < DIM / BKS; ++kt) {
    const int k0 = kt * BKS;
    async_copy16(Xb + (size_t)(n0 + srow) * DIM + k0 + sk8, &As[wave * 512]);
    async_copy16(Xb + (size_t)(n0 + srow + 64) * DIM + k0 + sk8, &As[2048 + wave * 512]);
    async_copy16(WbT + (size_t)srow * DIM + k0 + sk8, &Bs[wave * 512]);
    async_copy16(WbT + (size_t)(srow + 64) * DIM + k0 + sk8, &Bs[2048 + wave * 512]);
    __syncthreads();
    short8 a[4], b[4];
#pragma unroll
    for (int i = 0; i < 4; ++i) {
      const int R = wr * 64 + i * 16 + fr;
      a[i] = *(const short8*)&As[R * BKS + swz_slot(R, g) * 8];
    }
#pragma unroll
    for (int j = 0; j < 4; ++j) {
      const int R = wc * 64 + j * 16 + fr;
      b[j] = *(const short8*)&Bs[R * BKS + swz_slot(R, g) * 8];
    }
#pragma unroll
    for (int i = 0; i < 4; ++i)
#pragma unroll
      for (int j = 0; j < 4; ++j)
        acc[i][j] = __builtin_amdgcn_mfma_f32_16x16x32_bf16(a[i], b[j], acc[i][j], 0, 0, 0);
    __syncthreads();
  }

  const int rq = g * 4;
#pragma unroll
  for (int i = 0; i < 4; ++i)
#pragma unroll
    for (int j = 0; j < 4; ++j)
#pragma unroll
      for (int q = 0; q < 4; ++q)
        lg[wr * 64 + i * 16 + rq + q][wc * 64 + j * 16 + fr] = acc[i][j][q];
  __syncthreads();

  const int row = tid >> 1, half = tid & 1;
  const float4* lr = (const float4*)(&lg[row][half * 64]);
  float mx = -3.4e38f;
#pragma unroll
  for (int c = 0; c < 16; ++c) {
    float4 v = lr[c];
    mx = fmaxf(mx, fmaxf(fmaxf(v.x, v.y), fmaxf(v.z, v.w)));
  }
  mx = fmaxf(mx, __shfl_xor(mx, 1));
  float s = 0.f;
#pragma unroll
  for (int c = 0; c < 16; ++c) {
    float4 v = lr[c];
    s += __expf(v.x - mx) + __expf(v.y - mx) + __expf(v.z - mx) + __expf(v.w - mx);
  }
  s += __shfl_xor(s, 1);
  if (half == 0) phi_b[n0 + row] = mx + logf(s);
}

// =====================================================================
// Kernel 4: fused bf16 MFMA GEMM (x @ target^T) + min_n(phi_b[n]-dot)
// 256x256 tile, K-tile=64 (2 k-steps of 32), 8 waves (2Mx4N).
// 3-stage pipeline: MFMA(regs t) || ds_read(regs t-next-phase) ||
// stage(tile t+2 into buf[t&1]). ks-major LDS [2][256][32] makes the
// phase-granular WAR safe. 2 barriers per K-tile; vmcnt(4) counted.
// =====================================================================
__device__ __forceinline__ void stage_ks(const short* __restrict__ src, short* region,
                                         int kglob, int tid) {
  const int r0 = tid >> 2;                       // 0..127
  const int s0 = (tid & 3) ^ ((r0 >> 1) & 3);    // pre-swizzled source slot
  short* wvb = region + (tid >> 6) * 512;        // wave-uniform linear dest
  async_copy16(src + (size_t)r0 * DIM + kglob + s0 * 8, wvb);
  async_copy16(src + (size_t)(128 + r0) * DIM + kglob + s0 * 8, wvb + 4096);
}

__device__ __forceinline__ void mfma32(const short8 (&a)[8], const short8 (&b)[4],
                                       f32x4 (&acc)[8][4]) {
  __builtin_amdgcn_s_setprio(1);
#pragma unroll
  for (int i = 0; i < 8; ++i)
#pragma unroll
    for (int j = 0; j < 4; ++j)
      acc[i][j] = __builtin_amdgcn_mfma_f32_16x16x32_bf16(a[i], b[j], acc[i][j], 0, 0, 0);
  __builtin_amdgcn_s_setprio(0);
}

// STG: stage tile t+2.  VMC: vmcnt at PhA end (4 steady, 0 tail, -1 none).
// PRE: read (t+1).ks0 during PhB.
template <bool STG, int VMC, bool PRE>
__device__ __forceinline__ void ktile(const short* __restrict__ cur,
                                      const short* __restrict__ nxt,
                                      short* stg,
                                      const short* __restrict__ Xrow,
                                      const short* __restrict__ Trow,
                                      int kg2, int tid, int aoff, int boff,
                                      short8 (&rA0)[8], short8 (&rB0)[4],
                                      short8 (&rA1)[8], short8 (&rB1)[4],
                                      f32x4 (&acc)[8][4]) {
  // ---- Phase A: MFMA(t.ks0) ; ds_read t.ks1 ; stage (t+2).ks0 ----
#pragma unroll
  for (int i = 0; i < 8; ++i) rA1[i] = *(const short8*)(cur + KS1 + aoff + i * 512);
#pragma unroll
  for (int j = 0; j < 4; ++j) rB1[j] = *(const short8*)(cur + BREG + KS1 + boff + j * 512);
  if (STG) {
    stage_ks(Xrow, stg, kg2, tid);
    stage_ks(Trow, stg + BREG, kg2, tid);
  }
  mfma32(rA0, rB0, acc);
  if (VMC == 4) asm volatile("s_waitcnt vmcnt(4)" ::: "memory");
  else if (VMC == 0) asm volatile("s_waitcnt vmcnt(0)" ::: "memory");
  asm volatile("s_waitcnt lgkmcnt(0)" ::: "memory");
  __builtin_amdgcn_s_barrier();
  // ---- Phase B: MFMA(t.ks1) ; ds_read (t+1).ks0 ; stage (t+2).ks1 ----
  if (PRE) {
#pragma unroll
    for (int i = 0; i < 8; ++i) rA0[i] = *(const short8*)(nxt + aoff + i * 512);
#pragma unroll
    for (int j = 0; j < 4; ++j) rB0[j] = *(const short8*)(nxt + BREG + boff + j * 512);
  }
  if (STG) {
    stage_ks(Xrow, stg + KS1, kg2 + 32, tid);
    stage_ks(Trow, stg + BREG + KS1, kg2 + 32, tid);
  }
  mfma32(rA1, rB1, acc);
  asm volatile("s_waitcnt lgkmcnt(0)" ::: "memory");
  __builtin_amdgcn_s_barrier();
}

__global__ __launch_bounds__(512, 2)
void gemm_min_kernel(const short* __restrict__ Xb, const short* __restrict__ Tb,
                     const float* __restrict__ phi_b, unsigned* __restrict__ keys) {
  __shared__ __align__(16) short buf[2][32768];   // 128 KiB

  const int tid = threadIdx.x;
  const int wave = tid >> 6, lane = tid & 63;
  const int wm = wave >> 2, wn = wave & 3;
  const int fr = lane & 15, g = lane >> 4;

  int bid = blockIdx.x;
  bid = (bid & 7) * 128 + (bid >> 3);   // XCD-chunked swizzle (1024 = 8*128, bijective)
  const int m0 = (bid & 31) * BN;
  const int n0 = (bid >> 5) * BM;
  const short* Xrow = Xb + (size_t)n0 * DIM;
  const short* Trow = Tb + (size_t)m0 * DIM;

  const int key8 = (g ^ ((fr >> 1) & 3)) * 8;
  const int aoff = (wm * 128 + fr) * 32 + key8;
  const int boff = (wn * 64 + fr) * 32 + key8;

  f32x4 acc[8][4] = {};
  short8 rA0[8], rA1[8], rB0[4], rB1[4];

  // prologue: stage tiles 0 and 1 (16 loads); retire tile 0; load t0.ks0 regs
  stage_ks(Xrow, buf[0], 0, tid);            stage_ks(Trow, buf[0] + BREG, 0, tid);
  stage_ks(Xrow, buf[0] + KS1, 32, tid);     stage_ks(Trow, buf[0] + BREG + KS1, 32, tid);
  stage_ks(Xrow, buf[1], 64, tid);           stage_ks(Trow, buf[1] + BREG, 64, tid);
  stage_ks(Xrow, buf[1] + KS1, 96, tid);     stage_ks(Trow, buf[1] + BREG + KS1, 96, tid);
  asm volatile("s_waitcnt vmcnt(8)" ::: "memory");
  __builtin_amdgcn_s_barrier();
#pragma unroll
  for (int i = 0; i < 8; ++i) rA0[i] = *(const short8*)(buf[0] + aoff + i * 512);
#pragma unroll
  for (int j = 0; j < 4; ++j) rB0[j] = *(const short8*)(buf[0] + BREG + boff + j * 512);

#pragma unroll 1
  for (int t = 0; t < 6; ++t) {
    ktile<true, 4, true>(buf[t & 1], buf[(t + 1) & 1], buf[t & 1],
                         Xrow, Trow, (t + 2) * 64, tid, aoff, boff,
                         rA0, rB0, rA1, rB1, acc);
  }
  ktile<false, 0, true>(buf[0], buf[1], buf[0], Xrow, Trow, 0, tid, aoff, boff,
                        rA0, rB0, rA1, rB1, acc);
  ktile<false, -1, false>(buf[1], buf[0], buf[1], Xrow, Trow, 0, tid, aoff, boff,
                          rA0, rB0, rA1, rB1, acc);

  // Epilogue: v = phi_b[n] - dot(n,m); per-column min over wave's 128 rows.
  // C/D layout: col = lane&15, row = (lane>>4)*4 + q
  const int rq = g * 4;
  float mv[4] = {3.4e38f, 3.4e38f, 3.4e38f, 3.4e38f};
#pragma unroll
  for (int i = 0; i < 8; ++i) {
    float pb[4];
#pragma unroll
    for (int q = 0; q < 4; ++q) pb[q] = phi_b[n0 + wm * 128 + i * 16 + rq + q];
#pragma unroll
    for (int j = 0; j < 4; ++j)
#pragma unroll
      for (int q = 0; q < 4; ++q) mv[j] = fminf(mv[j], pb[q] - acc[i][j][q]);
  }
#pragma unroll
  for (int j = 0; j < 4; ++j) {
    float v = mv[j];
    v = fminf(v, __shfl_xor(v, 16));
    v = fminf(v, __shfl_xor(v, 32));
    if (g == 0) {
      atomicMin(&keys[m0 + wn * 64 + j * 16 + fr], fenc(v));
    }
  }
}

// =====================================================================
// Kernel 5: final reduce: mean(phi_k) + mean(phi_c). 1 block, 1024 thr.
// =====================================================================
__global__ __launch_bounds__(1024)
void finalize_kernel(const float* __restrict__ xsq, const float* __restrict__ phi_b,
                     const float* __restrict__ tsq, const unsigned* __restrict__ keys,
                     float* __restrict__ out) {
  const int t = threadIdx.x;
  double sk = 0.0, sc = 0.0;
  for (int n = t; n < N_PTS; n += 1024) sk += 0.5 * (double)xsq[n] - (double)phi_b[n];
  for (int m = t; m < M_PTS; m += 1024) sc += 0.5 * (double)tsq[m] + (double)fdec(keys[m]);
  const int lane = t & 63, wv = t >> 6;
#pragma unroll
  for (int m = 1; m <= 32; m <<= 1) {
    sk += __shfl_xor(sk, m);
    sc += __shfl_xor(sc, m);
  }
  __shared__ double pk[16], pc[16];
  if (lane == 0) { pk[wv] = sk; pc[wv] = sc; }
  __syncthreads();
  if (t == 0) {
    double a = 0.0, c = 0.0;
#pragma unroll
    for (int i = 0; i < 16; ++i) { a += pk[i]; c += pc[i]; }
    out[0] = (float)(a / N_PTS + c / M_PTS);
  }
}

// =====================================================================
extern "C" void kernel_launch(void* const* d_in, const int* in_sizes, int n_in,
                              void* d_out, int out_size, void* d_ws, size_t ws_size,
                              hipStream_t stream) {
  const float* x = (const float*)d_in[0];
  const float* tgt = (const float*)d_in[1];
  const float* W = (const float*)d_in[2];

  char* ws = (char*)d_ws;
  const size_t XB_BYTES = (size_t)N_PTS * DIM * 2;
  const size_t TB_BYTES = (size_t)M_PTS * DIM * 2;
  const size_t WT_BYTES = (size_t)KDIM * DIM * 2;
  unsigned short* Xb = (unsigned short*)ws;
  unsigned short* Tb = (unsigned short*)(ws + XB_BYTES);
  unsigned short* WbT = (unsigned short*)(ws + XB_BYTES + TB_BYTES);
  float* phi_b = (float*)(ws + XB_BYTES + TB_BYTES + WT_BYTES);
  float* xsq = phi_b + N_PTS;
  float* tsq = xsq + N_PTS;
  unsigned* keys = (unsigned*)(tsq + M_PTS);

  cast_rows_kernel<<<(N_PTS + M_PTS) / 4, 256, 0, stream>>>(x, tgt, Xb, Tb, xsq, tsq, keys);
  prep_w_kernel<<<(KDIM * DIM) / 256, 256, 0, stream>>>(W, WbT);
  phi_b_kernel<<<N_PTS / BT, 256, 0, stream>>>((const short*)Xb, (const short*)WbT, phi_b);
  gemm_min_kernel<<<(N_PTS / BM) * (M_PTS / BN), 512, 0, stream>>>(
      (const short*)Xb, (const short*)Tb, phi_b, keys);
  finalize_kernel<<<1, 1024, 0, stream>>>(xsq, phi_b, tsq, keys, (float*)d_out);
}

// Round 7
// 101.833 us; speedup vs baseline: 1.0381x; 1.0149x over previous
//
#include <hip/hip_runtime.h>
#include <hip/hip_bf16.h>
#include <stdint.h>

typedef __attribute__((ext_vector_type(8))) short short8;
typedef __attribute__((ext_vector_type(4))) float f32x4;

#define N_PTS 8192
#define M_PTS 8192
#define DIM   512
#define KDIM  128
#define BT    128   // phi_b tile
#define BKS   32
#define BM    256   // gemm tile
#define BN    256

// ---- float <-> order-preserving uint key (for atomicMin on float) ----
__device__ __forceinline__ unsigned fenc(float f) {
  unsigned u = __float_as_uint(f);
  return (u & 0x80000000u) ? ~u : (u | 0x80000000u);
}
__device__ __forceinline__ float fdec(unsigned k) {
  unsigned u = (k & 0x80000000u) ? (k ^ 0x80000000u) : ~k;
  return __uint_as_float(u);
}

__device__ __forceinline__ unsigned short f2bf(float f) {
  union { __hip_bfloat16 h; unsigned short u; } c;
  c.h = __float2bfloat16(f);
  return c.u;
}

// ---- async global -> LDS, 16B per lane ----
__device__ __forceinline__ void async_copy16(const void* g, void* l) {
  __builtin_amdgcn_global_load_lds(
      (const __attribute__((address_space(1))) void*)g,
      (__attribute__((address_space(3))) void*)l, 16, 0, 0);
}

// ---- LDS slot swizzle (verified: conflicts -> 0): 4 slots of 16B per 64B row
__device__ __forceinline__ int swz_slot(int row, int slot) {
  return slot ^ ((row >> 1) & 3);
}

#define BARRIER __builtin_amdgcn_s_barrier()
#define LGKM0 do { asm volatile("s_waitcnt lgkmcnt(0)" ::: "memory"); \
                   __builtin_amdgcn_sched_barrier(0); } while (0)

// =====================================================================
// Kernel 1: streaming cast x & target -> bf16, row sumsq, key init.
// =====================================================================
__global__ __launch_bounds__(256)
void cast_rows_kernel(const float* __restrict__ x, const float* __restrict__ tgt,
                      unsigned short* __restrict__ Xb, unsigned short* __restrict__ Tb,
                      float* __restrict__ xsq, float* __restrict__ tsq,
                      unsigned* __restrict__ keys) {
  const int gw = (blockIdx.x * 256 + threadIdx.x) >> 6;
  const int lane = threadIdx.x & 63;
  const float* src;
  unsigned short* dst;
  float* sq;
  int trow = -1;
  if (gw < N_PTS) {
    src = x + (size_t)gw * DIM;
    dst = Xb + (size_t)gw * DIM;
    sq = xsq + gw;
  } else {
    trow = gw - N_PTS;
    src = tgt + (size_t)trow * DIM;
    dst = Tb + (size_t)trow * DIM;
    sq = tsq + trow;
  }
  float s = 0.f;
#pragma unroll
  for (int i = 0; i < 2; ++i) {
    float4 v = ((const float4*)src)[i * 64 + lane];
    s += v.x * v.x + v.y * v.y + v.z * v.z + v.w * v.w;
    ushort4 o;
    o.x = f2bf(v.x); o.y = f2bf(v.y); o.z = f2bf(v.z); o.w = f2bf(v.w);
    ((ushort4*)dst)[i * 64 + lane] = o;
  }
#pragma unroll
  for (int m = 1; m <= 32; m <<= 1) s += __shfl_xor(s, m);
  if (lane == 0) {
    *sq = s;
    if (trow >= 0) keys[trow] = 0xFFFFFFFFu;
  }
}

// =====================================================================
// Kernel 2: W [D][K] fp32 -> WbT [K][D] bf16 (transposed cast)
// =====================================================================
__global__ __launch_bounds__(256)
void prep_w_kernel(const float* __restrict__ W, unsigned short* __restrict__ WbT) {
  const int o = blockIdx.x * 256 + threadIdx.x;
  const int k = o >> 9, d = o & 511;
  WbT[o] = f2bf(W[d * KDIM + k]);
}

// =====================================================================
// Kernel 3: phi_b = logsumexp(Xb @ WbT^T) via MFMA + in-LDS logsumexp.
// =====================================================================
__global__ __launch_bounds__(256)
void phi_b_kernel(const short* __restrict__ Xb, const short* __restrict__ WbT,
                  float* __restrict__ phi_b) {
  __shared__ __align__(16) short As[BT * BKS];
  __shared__ __align__(16) short Bs[BT * BKS];
  __shared__ __align__(16) float lg[128][136];

  const int tid = threadIdx.x;
  const int wave = tid >> 6, lane = tid & 63;
  const int n0 = blockIdx.x * BT;
  const int srow = tid >> 2;
  const int sk8 = swz_slot(srow, tid & 3) * 8;
  const int wr = wave >> 1, wc = wave & 1;
  const int fr = lane & 15, g = lane >> 4;

  f32x4 acc[4][4] = {};
  for (int kt = 0; kt < DIM / BKS; ++kt) {
    const int k0 = kt * BKS;
    async_copy16(Xb + (size_t)(n0 + srow) * DIM + k0 + sk8, &As[wave * 512]);
    async_copy16(Xb + (size_t)(n0 + srow + 64) * DIM + k0 + sk8, &As[2048 + wave * 512]);
    async_copy16(WbT + (size_t)srow * DIM + k0 + sk8, &Bs[wave * 512]);
    async_copy16(WbT + (size_t)(srow + 64) * DIM + k0 + sk8, &Bs[2048 + wave * 512]);
    __syncthreads();
    short8 a[4], b[4];
#pragma unroll
    for (int i = 0; i < 4; ++i) {
      const int R = wr * 64 + i * 16 + fr;
      a[i] = *(const short8*)&As[R * BKS + swz_slot(R, g) * 8];
    }
#pragma unroll
    for (int j = 0; j < 4; ++j) {
      const int R = wc * 64 + j * 16 + fr;
      b[j] = *(const short8*)&Bs[R * BKS + swz_slot(R, g) * 8];
    }
#pragma unroll
    for (int i = 0; i < 4; ++i)
#pragma unroll
      for (int j = 0; j < 4; ++j)
        acc[i][j] = __builtin_amdgcn_mfma_f32_16x16x32_bf16(a[i], b[j], acc[i][j], 0, 0, 0);
    __syncthreads();
  }

  const int rq = g * 4;
#pragma unroll
  for (int i = 0; i < 4; ++i)
#pragma unroll
    for (int j = 0; j < 4; ++j)
#pragma unroll
      for (int q = 0; q < 4; ++q)
        lg[wr * 64 + i * 16 + rq + q][wc * 64 + j * 16 + fr] = acc[i][j][q];
  __syncthreads();

  const int row = tid >> 1, half = tid & 1;
  const float4* lr = (const float4*)(&lg[row][half * 64]);
  float mx = -3.4e38f;
#pragma unroll
  for (int c = 0; c < 16; ++c) {
    float4 v = lr[c];
    mx = fmaxf(mx, fmaxf(fmaxf(v.x, v.y), fmaxf(v.z, v.w)));
  }
  mx = fmaxf(mx, __shfl_xor(mx, 1));
  float s = 0.f;
#pragma unroll
  for (int c = 0; c < 16; ++c) {
    float4 v = lr[c];
    s += __expf(v.x - mx) + __expf(v.y - mx) + __expf(v.z - mx) + __expf(v.w - mx);
  }
  s += __shfl_xor(s, 1);
  if (half == 0) phi_b[n0 + row] = mx + logf(s);
}

// =====================================================================
// Kernel 4: fused bf16 MFMA GEMM (x @ target^T) + min_n(phi_b[n]-dot)
// Faithful m201-style 8-phase schedule. 256x256 tile, BK=64 as two
// K-halves (ks0/ks1), dbuf0 = even K-tiles, dbuf1 = odd (fixed).
// LDS per dbuf: A_ks0[256][32] @0, A_ks1 @8192, B_ks0 @16384, B_ks1 @24576.
// Phase: {4-8 ds_reads (in-phase quadrant) ; 1 half stage ; barrier ;
// lgkmcnt(0) ; setprio 16-MFMA ; [vmcnt(6) end-P2/P6 only] ; barrier}.
// Ledger: end-P2 wait retires <=P7(prev), end-P6 retires <=P3 — all
// WAR/RAW windows verified (see round-7 notes).
// =====================================================================
__device__ __forceinline__ void stage_half(const short* __restrict__ src, short* dst,
                                           int kcol, int tid) {
  const int r = tid >> 2;                      // 0..127
  const int s = (tid & 3) ^ ((r >> 1) & 3);    // pre-swizzled source slot
  short* wv = dst + (tid >> 6) * 512;          // wave-uniform linear dest
  async_copy16(src + (size_t)r * DIM + kcol + s * 8, wv);
  async_copy16(src + (size_t)(r + 128) * DIM + kcol + s * 8, wv + 4096);
}

__device__ __forceinline__ void mf16(const short8 (&a)[4], const short8 (&b)[4],
                                     f32x4 (&acc)[8][4], int base) {
  __builtin_amdgcn_s_setprio(1);
#pragma unroll
  for (int i = 0; i < 4; ++i)
#pragma unroll
    for (int j = 0; j < 4; ++j)
      acc[base + i][j] =
          __builtin_amdgcn_mfma_f32_16x16x32_bf16(a[i], b[j], acc[base + i][j], 0, 0, 0);
  __builtin_amdgcn_s_setprio(0);
}

template <bool STG, bool TAIL>
__device__ __forceinline__ void iter8(short* L0, short* L1,
                                      const short* __restrict__ Xrow,
                                      const short* __restrict__ Trow,
                                      int kb, int tid, int aoff, int boff,
                                      f32x4 (&acc)[8][4]) {
  short8 aA[4], aB[4], b0[4], b1[4];
  // ---- P1: Q1(T0) = (i0-3, ks0); stage A_ks1(T1) @ kb+96 ----
#pragma unroll
  for (int i = 0; i < 4; ++i) aA[i] = *(const short8*)(L0 + aoff + i * 512);
#pragma unroll
  for (int j = 0; j < 4; ++j) b0[j] = *(const short8*)(L0 + 16384 + boff + j * 512);
  stage_half(Xrow, L1 + 8192, kb + 96, tid);
  BARRIER; LGKM0;
  mf16(aA, b0, acc, 0);
  BARRIER;
  // ---- P2: Q2 = (i4-7, ks0); stage B_ks0(T0'') @ kb+128; vmcnt ----
#pragma unroll
  for (int i = 0; i < 4; ++i) aB[i] = *(const short8*)(L0 + aoff + (4 + i) * 512);
  if (STG) stage_half(Trow, L0 + 16384, kb + 128, tid);
  BARRIER; LGKM0;
  mf16(aB, b0, acc, 4);
  if (TAIL) asm volatile("s_waitcnt vmcnt(4)" ::: "memory");
  else      asm volatile("s_waitcnt vmcnt(6)" ::: "memory");
  BARRIER;
  // ---- P3: Q3 = (i0-3, ks1); stage A_ks0(T0'') @ kb+128 ----
#pragma unroll
  for (int i = 0; i < 4; ++i) aA[i] = *(const short8*)(L0 + 8192 + aoff + i * 512);
#pragma unroll
  for (int j = 0; j < 4; ++j) b1[j] = *(const short8*)(L0 + 24576 + boff + j * 512);
  if (STG) stage_half(Xrow, L0, kb + 128, tid);
  BARRIER; LGKM0;
  mf16(aA, b1, acc, 0);
  BARRIER;
  // ---- P4: Q4 = (i4-7, ks1); stage B_ks1(T0'') @ kb+160 ----
#pragma unroll
  for (int i = 0; i < 4; ++i) aB[i] = *(const short8*)(L0 + 8192 + aoff + (4 + i) * 512);
  if (STG) stage_half(Trow, L0 + 24576, kb + 160, tid);
  BARRIER; LGKM0;
  mf16(aB, b1, acc, 4);
  BARRIER;
  // ---- P5: Q1(T1); stage A_ks1(T0'') @ kb+160 ----
#pragma unroll
  for (int i = 0; i < 4; ++i) aA[i] = *(const short8*)(L1 + aoff + i * 512);
#pragma unroll
  for (int j = 0; j < 4; ++j) b0[j] = *(const short8*)(L1 + 16384 + boff + j * 512);
  if (STG) stage_half(Xrow, L0 + 8192, kb + 160, tid);
  BARRIER; LGKM0;
  mf16(aA, b0, acc, 0);
  BARRIER;
  // ---- P6: Q2(T1); stage B_ks0(T1'') @ kb+192; vmcnt ----
#pragma unroll
  for (int i = 0; i < 4; ++i) aB[i] = *(const short8*)(L1 + aoff + (4 + i) * 512);
  if (STG) stage_half(Trow, L1 + 16384, kb + 192, tid);
  BARRIER; LGKM0;
  mf16(aB, b0, acc, 4);
  if (TAIL) asm volatile("s_waitcnt vmcnt(0)" ::: "memory");
  else      asm volatile("s_waitcnt vmcnt(6)" ::: "memory");
  BARRIER;
  // ---- P7: Q3(T1); stage A_ks0(T1'') @ kb+192 ----
#pragma unroll
  for (int i = 0; i < 4; ++i) aA[i] = *(const short8*)(L1 + 8192 + aoff + i * 512);
#pragma unroll
  for (int j = 0; j < 4; ++j) b1[j] = *(const short8*)(L1 + 24576 + boff + j * 512);
  if (STG) stage_half(Xrow, L1, kb + 192, tid);
  BARRIER; LGKM0;
  mf16(aA, b1, acc, 0);
  BARRIER;
  // ---- P8: Q4(T1); stage B_ks1(T1'') @ kb+224 ----
#pragma unroll
  for (int i = 0; i < 4; ++i) aB[i] = *(const short8*)(L1 + 8192 + aoff + (4 + i) * 512);
  if (STG) stage_half(Trow, L1 + 24576, kb + 224, tid);
  BARRIER; LGKM0;
  mf16(aB, b1, acc, 4);
  BARRIER;
}

__global__ __launch_bounds__(512, 2)
void gemm_min_kernel(const short* __restrict__ Xb, const short* __restrict__ Tb,
                     const float* __restrict__ phi_b, unsigned* __restrict__ keys) {
  __shared__ __align__(16) short lds[65536];   // 128 KiB
  short* L0 = lds;
  short* L1 = lds + 32768;

  const int tid = threadIdx.x;
  const int wave = tid >> 6, lane = tid & 63;
  const int wm = wave >> 2, wn = wave & 3;
  const int fr = lane & 15, g = lane >> 4;

  int bid = blockIdx.x;
  bid = (bid & 7) * 128 + (bid >> 3);   // XCD-chunked swizzle (1024 = 8*128, bijective)
  const int m0 = (bid & 31) * BN;
  const int n0 = (bid >> 5) * BM;
  const short* Xrow = Xb + (size_t)n0 * DIM;
  const short* Trow = Tb + (size_t)m0 * DIM;

  const int key8 = (g ^ ((fr >> 1) & 3)) * 8;
  const int aoff = (wm * 128 + fr) * 32 + key8;
  const int boff = (wn * 64 + fr) * 32 + key8;

  // prologue: tile0 fully + tile1 {B_ks0, A_ks0, B_ks1}; A_ks1(t1) staged at P1
  stage_half(Trow, L0 + 16384, 0, tid);
  stage_half(Xrow, L0, 0, tid);
  stage_half(Trow, L0 + 24576, 32, tid);
  stage_half(Xrow, L0 + 8192, 32, tid);
  stage_half(Trow, L1 + 16384, 64, tid);
  stage_half(Xrow, L1, 64, tid);
  stage_half(Trow, L1 + 24576, 96, tid);
  asm volatile("s_waitcnt vmcnt(6)" ::: "memory");   // retire tile0's 8 loads
  BARRIER;

  f32x4 acc[8][4] = {};
  iter8<true, false>(L0, L1, Xrow, Trow, 0, tid, aoff, boff, acc);
  iter8<true, false>(L0, L1, Xrow, Trow, 128, tid, aoff, boff, acc);
  iter8<true, false>(L0, L1, Xrow, Trow, 256, tid, aoff, boff, acc);
  iter8<false, true>(L0, L1, Xrow, Trow, 384, tid, aoff, boff, acc);

  // Epilogue: v = phi_b[n] - dot(n,m); per-column min over wave's 128 rows.
  // C/D layout: col = lane&15, row = (lane>>4)*4 + q
  const int rq = g * 4;
  float mv[4] = {3.4e38f, 3.4e38f, 3.4e38f, 3.4e38f};
#pragma unroll
  for (int i = 0; i < 8; ++i) {
    float pb[4];
#pragma unroll
    for (int q = 0; q < 4; ++q) pb[q] = phi_b[n0 + wm * 128 + i * 16 + rq + q];
#pragma unroll
    for (int j = 0; j < 4; ++j)
#pragma unroll
      for (int q = 0; q < 4; ++q) mv[j] = fminf(mv[j], pb[q] - acc[i][j][q]);
  }
#pragma unroll
  for (int j = 0; j < 4; ++j) {
    float v = mv[j];
    v = fminf(v, __shfl_xor(v, 16));
    v = fminf(v, __shfl_xor(v, 32));
    if (g == 0) {
      atomicMin(&keys[m0 + wn * 64 + j * 16 + fr], fenc(v));
    }
  }
}

// =====================================================================
// Kernel 5: final reduce: mean(phi_k) + mean(phi_c). 1 block, 1024 thr.
// =====================================================================
__global__ __launch_bounds__(1024)
void finalize_kernel(const float* __restrict__ xsq, const float* __restrict__ phi_b,
                     const float* __restrict__ tsq, const unsigned* __restrict__ keys,
                     float* __restrict__ out) {
  const int t = threadIdx.x;
  double sk = 0.0, sc = 0.0;
  for (int n = t; n < N_PTS; n += 1024) sk += 0.5 * (double)xsq[n] - (double)phi_b[n];
  for (int m = t; m < M_PTS; m += 1024) sc += 0.5 * (double)tsq[m] + (double)fdec(keys[m]);
  const int lane = t & 63, wv = t >> 6;
#pragma unroll
  for (int m = 1; m <= 32; m <<= 1) {
    sk += __shfl_xor(sk, m);
    sc += __shfl_xor(sc, m);
  }
  __shared__ double pk[16], pc[16];
  if (lane == 0) { pk[wv] = sk; pc[wv] = sc; }
  __syncthreads();
  if (t == 0) {
    double a = 0.0, c = 0.0;
#pragma unroll
    for (int i = 0; i < 16; ++i) { a += pk[i]; c += pc[i]; }
    out[0] = (float)(a / N_PTS + c / M_PTS);
  }
}

// =====================================================================
extern "C" void kernel_launch(void* const* d_in, const int* in_sizes, int n_in,
                              void* d_out, int out_size, void* d_ws, size_t ws_size,
                              hipStream_t stream) {
  const float* x = (const float*)d_in[0];
  const float* tgt = (const float*)d_in[1];
  const float* W = (const float*)d_in[2];

  char* ws = (char*)d_ws;
  const size_t XB_BYTES = (size_t)N_PTS * DIM * 2;
  const size_t TB_BYTES = (size_t)M_PTS * DIM * 2;
  const size_t WT_BYTES = (size_t)KDIM * DIM * 2;
  unsigned short* Xb = (unsigned short*)ws;
  unsigned short* Tb = (unsigned short*)(ws + XB_BYTES);
  unsigned short* WbT = (unsigned short*)(ws + XB_BYTES + TB_BYTES);
  float* phi_b = (float*)(ws + XB_BYTES + TB_BYTES + WT_BYTES);
  float* xsq = phi_b + N_PTS;
  float* tsq = xsq + N_PTS;
  unsigned* keys = (unsigned*)(tsq + M_PTS);

  cast_rows_kernel<<<(N_PTS + M_PTS) / 4, 256, 0, stream>>>(x, tgt, Xb, Tb, xsq, tsq, keys);
  prep_w_kernel<<<(KDIM * DIM) / 256, 256, 0, stream>>>(W, WbT);
  phi_b_kernel<<<N_PTS / BT, 256, 0, stream>>>((const short*)Xb, (const short*)WbT, phi_b);
  gemm_min_kernel<<<(N_PTS / BM) * (M_PTS / BN), 512, 0, stream>>>(
      (const short*)Xb, (const short*)Tb, phi_b, keys);
  finalize_kernel<<<1, 1024, 0, stream>>>(xsq, phi_b, tsq, keys, (float*)d_out);
}

// Round 8
// 92.240 us; speedup vs baseline: 1.1460x; 1.1040x over previous
//
#include <hip/hip_runtime.h>
#include <hip/hip_bf16.h>
#include <stdint.h>

typedef __attribute__((ext_vector_type(8))) short short8;
typedef __attribute__((ext_vector_type(4))) float f32x4;

#define N_PTS 8192
#define M_PTS 8192
#define DIM   512
#define KDIM  128
#define BT    128   // phi_b tile
#define BKS   32

// ---- float <-> order-preserving uint key (for atomicMin on float) ----
__device__ __forceinline__ unsigned fenc(float f) {
  unsigned u = __float_as_uint(f);
  return (u & 0x80000000u) ? ~u : (u | 0x80000000u);
}
__device__ __forceinline__ float fdec(unsigned k) {
  unsigned u = (k & 0x80000000u) ? (k ^ 0x80000000u) : ~k;
  return __uint_as_float(u);
}

__device__ __forceinline__ unsigned short f2bf(float f) {
  union { __hip_bfloat16 h; unsigned short u; } c;
  c.h = __float2bfloat16(f);
  return c.u;
}

// ---- float -> OCP e4m3fn, RNE, flush |f|<2^-6 to 0 (x,t ~ N(0,1)) ----
__device__ __forceinline__ unsigned char f2e4m3(float f) {
  unsigned u = __float_as_uint(f);
  unsigned s = (u >> 24) & 0x80;
  unsigned mag = u & 0x7fffffffu;
  unsigned r = mag + 0x0007ffffu + ((mag >> 20) & 1u);  // RNE to 3 mantissa bits
  int e = (int)(r >> 23) - 127;
  if (e < -6) return (unsigned char)s;                  // flush tiny to zero
  unsigned m = (r >> 20) & 7u;
  return (unsigned char)(s | (unsigned)((e + 7) << 3) | m);
}

// ---- async global -> LDS, 16B per lane ----
__device__ __forceinline__ void async_copy16(const void* g, void* l) {
  __builtin_amdgcn_global_load_lds(
      (const __attribute__((address_space(1))) void*)g,
      (__attribute__((address_space(3))) void*)l, 16, 0, 0);
}

// ---- bf16 LDS slot swizzle (phi_b kernel, verified 0 conflicts) ----
__device__ __forceinline__ int swz_slot(int row, int slot) {
  return slot ^ ((row >> 1) & 3);
}

#define BARRIER __builtin_amdgcn_s_barrier()
#define LGKM0 do { asm volatile("s_waitcnt lgkmcnt(0)" ::: "memory"); \
                   __builtin_amdgcn_sched_barrier(0); } while (0)

// =====================================================================
// Kernel 1: stream x & target: x -> Xb(bf16)+Xf8(e4m3)+xsq;
//           t -> Tf8(e4m3)+tsq; key init. One wave per row.
// =====================================================================
__global__ __launch_bounds__(256)
void cast_rows_kernel(const float* __restrict__ x, const float* __restrict__ tgt,
                      unsigned short* __restrict__ Xb, unsigned char* __restrict__ Xf8,
                      unsigned char* __restrict__ Tf8,
                      float* __restrict__ xsq, float* __restrict__ tsq,
                      unsigned* __restrict__ keys) {
  const int gw = (blockIdx.x * 256 + threadIdx.x) >> 6;
  const int lane = threadIdx.x & 63;
  float s = 0.f;
  if (gw < N_PTS) {
    const float* src = x + (size_t)gw * DIM;
    unsigned short* db = Xb + (size_t)gw * DIM;
    unsigned char* d8 = Xf8 + (size_t)gw * DIM;
#pragma unroll
    for (int i = 0; i < 2; ++i) {
      float4 v = ((const float4*)src)[i * 64 + lane];
      s += v.x * v.x + v.y * v.y + v.z * v.z + v.w * v.w;
      ushort4 ob;
      ob.x = f2bf(v.x); ob.y = f2bf(v.y); ob.z = f2bf(v.z); ob.w = f2bf(v.w);
      ((ushort4*)db)[i * 64 + lane] = ob;
      uchar4 o8;
      o8.x = f2e4m3(v.x); o8.y = f2e4m3(v.y); o8.z = f2e4m3(v.z); o8.w = f2e4m3(v.w);
      ((uchar4*)d8)[i * 64 + lane] = o8;
    }
#pragma unroll
    for (int m = 1; m <= 32; m <<= 1) s += __shfl_xor(s, m);
    if (lane == 0) xsq[gw] = s;
  } else {
    const int tr = gw - N_PTS;
    const float* src = tgt + (size_t)tr * DIM;
    unsigned char* d8 = Tf8 + (size_t)tr * DIM;
#pragma unroll
    for (int i = 0; i < 2; ++i) {
      float4 v = ((const float4*)src)[i * 64 + lane];
      s += v.x * v.x + v.y * v.y + v.z * v.z + v.w * v.w;
      uchar4 o8;
      o8.x = f2e4m3(v.x); o8.y = f2e4m3(v.y); o8.z = f2e4m3(v.z); o8.w = f2e4m3(v.w);
      ((uchar4*)d8)[i * 64 + lane] = o8;
    }
#pragma unroll
    for (int m = 1; m <= 32; m <<= 1) s += __shfl_xor(s, m);
    if (lane == 0) { tsq[tr] = s; keys[tr] = 0xFFFFFFFFu; }
  }
}

// =====================================================================
// Kernel 2: W [D][K] fp32 -> WbT [K][D] bf16 (transposed cast)
// =====================================================================
__global__ __launch_bounds__(256)
void prep_w_kernel(const float* __restrict__ W, unsigned short* __restrict__ WbT) {
  const int o = blockIdx.x * 256 + threadIdx.x;
  const int k = o >> 9, d = o & 511;
  WbT[o] = f2bf(W[d * KDIM + k]);
}

// =====================================================================
// Kernel 3: phi_b = logsumexp(Xb @ WbT^T) via bf16 MFMA (unchanged).
// =====================================================================
__global__ __launch_bounds__(256)
void phi_b_kernel(const short* __restrict__ Xb, const short* __restrict__ WbT,
                  float* __restrict__ phi_b) {
  __shared__ __align__(16) short As[BT * BKS];
  __shared__ __align__(16) short Bs[BT * BKS];
  __shared__ __align__(16) float lg[128][136];

  const int tid = threadIdx.x;
  const int wave = tid >> 6, lane = tid & 63;
  const int n0 = blockIdx.x * BT;
  const int srow = tid >> 2;
  const int sk8 = swz_slot(srow, tid & 3) * 8;
  const int wr = wave >> 1, wc = wave & 1;
  const int fr = lane & 15, g = lane >> 4;

  f32x4 acc[4][4] = {};
  for (int kt = 0; kt < DIM / BKS; ++kt) {
    const int k0 = kt * BKS;
    async_copy16(Xb + (size_t)(n0 + srow) * DIM + k0 + sk8, &As[wave * 512]);
    async_copy16(Xb + (size_t)(n0 + srow + 64) * DIM + k0 + sk8, &As[2048 + wave * 512]);
    async_copy16(WbT + (size_t)srow * DIM + k0 + sk8, &Bs[wave * 512]);
    async_copy16(WbT + (size_t)(srow + 64) * DIM + k0 + sk8, &Bs[2048 + wave * 512]);
    __syncthreads();
    short8 a[4], b[4];
#pragma unroll
    for (int i = 0; i < 4; ++i) {
      const int R = wr * 64 + i * 16 + fr;
      a[i] = *(const short8*)&As[R * BKS + swz_slot(R, g) * 8];
    }
#pragma unroll
    for (int j = 0; j < 4; ++j) {
      const int R = wc * 64 + j * 16 + fr;
      b[j] = *(const short8*)&Bs[R * BKS + swz_slot(R, g) * 8];
    }
#pragma unroll
    for (int i = 0; i < 4; ++i)
#pragma unroll
      for (int j = 0; j < 4; ++j)
        acc[i][j] = __builtin_amdgcn_mfma_f32_16x16x32_bf16(a[i], b[j], acc[i][j], 0, 0, 0);
    __syncthreads();
  }

  const int rq = g * 4;
#pragma unroll
  for (int i = 0; i < 4; ++i)
#pragma unroll
    for (int j = 0; j < 4; ++j)
#pragma unroll
      for (int q = 0; q < 4; ++q)
        lg[wr * 64 + i * 16 + rq + q][wc * 64 + j * 16 + fr] = acc[i][j][q];
  __syncthreads();

  const int row = tid >> 1, half = tid & 1;
  const float4* lr = (const float4*)(&lg[row][half * 64]);
  float mx = -3.4e38f;
#pragma unroll
  for (int c = 0; c < 16; ++c) {
    float4 v = lr[c];
    mx = fmaxf(mx, fmaxf(fmaxf(v.x, v.y), fmaxf(v.z, v.w)));
  }
  mx = fmaxf(mx, __shfl_xor(mx, 1));
  float s = 0.f;
#pragma unroll
  for (int c = 0; c < 16; ++c) {
    float4 v = lr[c];
    s += __expf(v.x - mx) + __expf(v.y - mx) + __expf(v.z - mx) + __expf(v.w - mx);
  }
  s += __shfl_xor(s, 1);
  if (half == 0) phi_b[n0 + row] = mx + logf(s);
}

// =====================================================================
// Kernel 4: fused fp8 MFMA GEMM (x @ target^T) + min_n(phi_b[n]-dot)
// 256x256 tile, BK=64, 8 waves (2Mx4N), 8-phase m201 schedule.
// LDS 64KB: L0/L1 = 32KB dbuf {A[256][64B] @0, B @16384}, halves = 128
// rows (8KB = ONE global_load_lds half-stage). Row swizzle: 16B block
// b -> b ^ ((row>>1)&3) (2-way bank alias = free for ds_read_b64).
// Stage slots: P4..P7 = T0''(kb+128, L0); P8+P1..P3(next) = T1-next
// (kb+192, L1). vmcnt(1) at end-P4 (retires this iter's T1) and
// end-P8 (retires T0''); tail vmcnt(0). WAR/RAW ledger verified.
// =====================================================================
__device__ __forceinline__ void stg8(const unsigned char* __restrict__ mat,
                                     int rowbase, int kbyte,
                                     unsigned char* lds8, int dst, int tid) {
  const int r = tid >> 2, d = tid & 3;
  async_copy16(mat + (size_t)(rowbase + r) * DIM + kbyte + ((d ^ ((r >> 1) & 3)) << 4),
               lds8 + dst + (tid >> 6) * 1024);
}

__device__ __forceinline__ void mf16f8(const long (&a)[4], const long (&b)[4],
                                       f32x4 (&acc)[8][4], int base) {
  __builtin_amdgcn_s_setprio(1);
#pragma unroll
  for (int i = 0; i < 4; ++i)
#pragma unroll
    for (int j = 0; j < 4; ++j)
      acc[base + i][j] = __builtin_amdgcn_mfma_f32_16x16x32_fp8_fp8(
          a[i], b[j], acc[base + i][j], 0, 0, 0);
  __builtin_amdgcn_s_setprio(0);
}

// CONT: stage this iter's T1 tail (P1-P3). NEW: stage T0''/T1-next (P4-P8).
// VM4: vmcnt at end-P4 (1 steady, 0 tail). VM8: end-P8 (1 steady, -1 none).
template <bool CONT, bool NEW, int VM4, int VM8>
__device__ __forceinline__ void iter_f8(unsigned char* lds8,
                                        const unsigned char* __restrict__ Xf,
                                        const unsigned char* __restrict__ Tf,
                                        int n0, int m0, int kb, int tid,
                                        int aoff, int boff, f32x4 (&acc)[8][4]) {
  // L0 @0 (even tiles), L1 @32768 (odd). A @+0, B @+16384. half1 @+8192.
  long a[4], b0[4], b1[4];
  // ---- P1: Q1 = (i0-3, ks0) + b(ks0) on L0; stage B(L1,kb+64).h1 ----
#pragma unroll
  for (int i = 0; i < 4; ++i) a[i] = *(const long*)(lds8 + aoff + i * 1024);
#pragma unroll
  for (int j = 0; j < 4; ++j) b0[j] = *(const long*)(lds8 + boff + j * 1024);
  if (CONT) stg8(Tf, m0 + 128, kb + 64, lds8, 32768 + 16384 + 8192, tid);
  BARRIER; LGKM0;
  mf16f8(a, b0, acc, 0);
  BARRIER;
  // ---- P2: Q2 = (i4-7, ks0); stage A(L1,kb+64).h0 ----
#pragma unroll
  for (int i = 0; i < 4; ++i) a[i] = *(const long*)(lds8 + aoff + (4 + i) * 1024);
  if (CONT) stg8(Xf, n0, kb + 64, lds8, 32768, tid);
  BARRIER; LGKM0;
  mf16f8(a, b0, acc, 4);
  BARRIER;
  // ---- P3: Q3 = (i0-3, ks1) + b(ks1); stage A(L1,kb+64).h1 ----
#pragma unroll
  for (int i = 0; i < 4; ++i) a[i] = *(const long*)(lds8 + ((aoff + i * 1024) ^ 32));
#pragma unroll
  for (int j = 0; j < 4; ++j) b1[j] = *(const long*)(lds8 + ((boff + j * 1024) ^ 32));
  if (CONT) stg8(Xf, n0 + 128, kb + 64, lds8, 32768 + 8192, tid);
  BARRIER; LGKM0;
  mf16f8(a, b1, acc, 0);
  BARRIER;
  // ---- P4: Q4 = (i4-7, ks1); stage B(L0,kb+128).h0; vmcnt(VM4) ----
#pragma unroll
  for (int i = 0; i < 4; ++i) a[i] = *(const long*)(lds8 + ((aoff + (4 + i) * 1024) ^ 32));
  if (NEW) stg8(Tf, m0, kb + 128, lds8, 16384, tid);
  BARRIER; LGKM0;
  mf16f8(a, b1, acc, 4);
  if (VM4 == 1) asm volatile("s_waitcnt vmcnt(1)" ::: "memory");
  else if (VM4 == 0) asm volatile("s_waitcnt vmcnt(0)" ::: "memory");
  BARRIER;
  // ---- P5: Q1 on L1; stage B(L0,kb+128).h1 ----
#pragma unroll
  for (int i = 0; i < 4; ++i) a[i] = *(const long*)(lds8 + 32768 + aoff + i * 1024);
#pragma unroll
  for (int j = 0; j < 4; ++j) b0[j] = *(const long*)(lds8 + 32768 + boff + j * 1024);
  if (NEW) stg8(Tf, m0 + 128, kb + 128, lds8, 16384 + 8192, tid);
  BARRIER; LGKM0;
  mf16f8(a, b0, acc, 0);
  BARRIER;
  // ---- P6: Q2 on L1; stage A(L0,kb+128).h0 ----
#pragma unroll
  for (int i = 0; i < 4; ++i) a[i] = *(const long*)(lds8 + 32768 + aoff + (4 + i) * 1024);
  if (NEW) stg8(Xf, n0, kb + 128, lds8, 0, tid);
  BARRIER; LGKM0;
  mf16f8(a, b0, acc, 4);
  BARRIER;
  // ---- P7: Q3 on L1; stage A(L0,kb+128).h1 ----
#pragma unroll
  for (int i = 0; i < 4; ++i) a[i] = *(const long*)(lds8 + 32768 + ((aoff + i * 1024) ^ 32));
#pragma unroll
  for (int j = 0; j < 4; ++j) b1[j] = *(const long*)(lds8 + 32768 + ((boff + j * 1024) ^ 32));
  if (NEW) stg8(Xf, n0 + 128, kb + 128, lds8, 8192, tid);
  BARRIER; LGKM0;
  mf16f8(a, b1, acc, 0);
  BARRIER;
  // ---- P8: Q4 on L1; stage B(L1,kb+192).h0; vmcnt(VM8) ----
#pragma unroll
  for (int i = 0; i < 4; ++i) a[i] = *(const long*)(lds8 + 32768 + ((aoff + (4 + i) * 1024) ^ 32));
  if (NEW) stg8(Tf, m0, kb + 192, lds8, 32768 + 16384, tid);
  BARRIER; LGKM0;
  mf16f8(a, b1, acc, 4);
  if (VM8 == 1) asm volatile("s_waitcnt vmcnt(1)" ::: "memory");
  BARRIER;
}

__global__ __launch_bounds__(512, 2)
void gemm_min_kernel(const unsigned char* __restrict__ Xf, const unsigned char* __restrict__ Tf,
                     const float* __restrict__ phi_b, unsigned* __restrict__ keys) {
  __shared__ __align__(16) unsigned char lds8[65536];   // 64 KiB

  const int tid = threadIdx.x;
  const int wave = tid >> 6, lane = tid & 63;
  const int wm = wave >> 2, wn = wave & 3;
  const int fr = lane & 15, g = lane >> 4;

  // 2D XCD chunking: 8 chunks of 8n x 16m tiles -> ~3MB working set per XCD L2
  const int bid = blockIdx.x;
  const int xcd = bid & 7, idx = bid >> 3;
  const int nt = (xcd >> 1) * 8 + (idx >> 4);
  const int mt = (xcd & 1) * 16 + (idx & 15);
  const int n0 = nt * 256, m0 = mt * 256;

  // fragment byte offsets (ks0); ks1 = ^32. 16B-block swizzle key = (fr>>1)&3
  const int blk = (((g >> 1) ^ ((fr >> 1) & 3)) << 4) + (g & 1) * 8;
  const int aoff = (wm * 128 + fr) * 64 + blk;
  const int boff = 16384 + (wn * 64 + fr) * 64 + blk;

  // prologue: T0 (kb=0) 4 halves then T1 (kb=64) 4 halves; retire T0.
  stg8(Tf, m0, 0, lds8, 16384, tid);
  stg8(Tf, m0 + 128, 0, lds8, 16384 + 8192, tid);
  stg8(Xf, n0, 0, lds8, 0, tid);
  stg8(Xf, n0 + 128, 0, lds8, 8192, tid);
  stg8(Tf, m0, 64, lds8, 32768 + 16384, tid);
  stg8(Tf, m0 + 128, 64, lds8, 32768 + 16384 + 8192, tid);
  stg8(Xf, n0, 64, lds8, 32768, tid);
  stg8(Xf, n0 + 128, 64, lds8, 32768 + 8192, tid);
  asm volatile("s_waitcnt vmcnt(4)" ::: "memory");
  BARRIER;

  f32x4 acc[8][4] = {};
  iter_f8<false, true, 1, 1>(lds8, Xf, Tf, n0, m0, 0, tid, aoff, boff, acc);
  iter_f8<true, true, 1, 1>(lds8, Xf, Tf, n0, m0, 128, tid, aoff, boff, acc);
  iter_f8<true, true, 1, 1>(lds8, Xf, Tf, n0, m0, 256, tid, aoff, boff, acc);
  iter_f8<true, false, 0, -1>(lds8, Xf, Tf, n0, m0, 384, tid, aoff, boff, acc);

  // Epilogue: v = phi_b[n] - dot(n,m); per-column min over wave's 128 rows.
  // C/D layout (dtype-independent): col = lane&15, row = (lane>>4)*4 + q
  const int rq = g * 4;
  float mv[4] = {3.4e38f, 3.4e38f, 3.4e38f, 3.4e38f};
#pragma unroll
  for (int i = 0; i < 8; ++i) {
    float pb[4];
#pragma unroll
    for (int q = 0; q < 4; ++q) pb[q] = phi_b[n0 + wm * 128 + i * 16 + rq + q];
#pragma unroll
    for (int j = 0; j < 4; ++j)
#pragma unroll
      for (int q = 0; q < 4; ++q) mv[j] = fminf(mv[j], pb[q] - acc[i][j][q]);
  }
#pragma unroll
  for (int j = 0; j < 4; ++j) {
    float v = mv[j];
    v = fminf(v, __shfl_xor(v, 16));
    v = fminf(v, __shfl_xor(v, 32));
    if (g == 0) {
      atomicMin(&keys[m0 + wn * 64 + j * 16 + fr], fenc(v));
    }
  }
}

// =====================================================================
// Kernel 5: final reduce: mean(phi_k) + mean(phi_c). 1 block, 1024 thr.
// =====================================================================
__global__ __launch_bounds__(1024)
void finalize_kernel(const float* __restrict__ xsq, const float* __restrict__ phi_b,
                     const float* __restrict__ tsq, const unsigned* __restrict__ keys,
                     float* __restrict__ out) {
  const int t = threadIdx.x;
  double sk = 0.0, sc = 0.0;
  for (int n = t; n < N_PTS; n += 1024) sk += 0.5 * (double)xsq[n] - (double)phi_b[n];
  for (int m = t; m < M_PTS; m += 1024) sc += 0.5 * (double)tsq[m] + (double)fdec(keys[m]);
  const int lane = t & 63, wv = t >> 6;
#pragma unroll
  for (int m = 1; m <= 32; m <<= 1) {
    sk += __shfl_xor(sk, m);
    sc += __shfl_xor(sc, m);
  }
  __shared__ double pk[16], pc[16];
  if (lane == 0) { pk[wv] = sk; pc[wv] = sc; }
  __syncthreads();
  if (t == 0) {
    double a = 0.0, c = 0.0;
#pragma unroll
    for (int i = 0; i < 16; ++i) { a += pk[i]; c += pc[i]; }
    out[0] = (float)(a / N_PTS + c / M_PTS);
  }
}

// =====================================================================
extern "C" void kernel_launch(void* const* d_in, const int* in_sizes, int n_in,
                              void* d_out, int out_size, void* d_ws, size_t ws_size,
                              hipStream_t stream) {
  const float* x = (const float*)d_in[0];
  const float* tgt = (const float*)d_in[1];
  const float* W = (const float*)d_in[2];

  char* ws = (char*)d_ws;
  const size_t XB_BYTES = (size_t)N_PTS * DIM * 2;   // bf16 x (for phi_b)
  const size_t XF_BYTES = (size_t)N_PTS * DIM;       // fp8 x
  const size_t TF_BYTES = (size_t)M_PTS * DIM;       // fp8 t
  const size_t WT_BYTES = (size_t)KDIM * DIM * 2;
  unsigned short* Xb = (unsigned short*)ws;
  unsigned char* Xf8 = (unsigned char*)(ws + XB_BYTES);
  unsigned char* Tf8 = (unsigned char*)(ws + XB_BYTES + XF_BYTES);
  unsigned short* WbT = (unsigned short*)(ws + XB_BYTES + XF_BYTES + TF_BYTES);
  float* phi_b = (float*)(ws + XB_BYTES + XF_BYTES + TF_BYTES + WT_BYTES);
  float* xsq = phi_b + N_PTS;
  float* tsq = xsq + N_PTS;
  unsigned* keys = (unsigned*)(tsq + M_PTS);

  cast_rows_kernel<<<(N_PTS + M_PTS) / 4, 256, 0, stream>>>(x, tgt, Xb, Xf8, Tf8,
                                                            xsq, tsq, keys);
  prep_w_kernel<<<(KDIM * DIM) / 256, 256, 0, stream>>>(W, WbT);
  phi_b_kernel<<<N_PTS / BT, 256, 0, stream>>>((const short*)Xb, (const short*)WbT, phi_b);
  gemm_min_kernel<<<(N_PTS / 256) * (M_PTS / 256), 512, 0, stream>>>(Xf8, Tf8, phi_b, keys);
  finalize_kernel<<<1, 1024, 0, stream>>>(xsq, phi_b, tsq, keys, (float*)d_out);
}

// Round 9
// 87.554 us; speedup vs baseline: 1.2074x; 1.0535x over previous
//
#include <hip/hip_runtime.h>
#include <hip/hip_bf16.h>
#include <stdint.h>

typedef __attribute__((ext_vector_type(8))) short short8;
typedef __attribute__((ext_vector_type(4))) float f32x4;
typedef __attribute__((ext_vector_type(2))) long lpair;   // 16B = {ks0, ks1} fp8 frags

#define N_PTS 8192
#define M_PTS 8192
#define DIM   512
#define KDIM  128
#define BT    128   // phi_b tile
#define BKS   32

// ---- float <-> order-preserving uint key (for atomicMin on float) ----
__device__ __forceinline__ unsigned fenc(float f) {
  unsigned u = __float_as_uint(f);
  return (u & 0x80000000u) ? ~u : (u | 0x80000000u);
}
__device__ __forceinline__ float fdec(unsigned k) {
  unsigned u = (k & 0x80000000u) ? (k ^ 0x80000000u) : ~k;
  return __uint_as_float(u);
}

__device__ __forceinline__ unsigned short f2bf(float f) {
  union { __hip_bfloat16 h; unsigned short u; } c;
  c.h = __float2bfloat16(f);
  return c.u;
}

// ---- float -> OCP e4m3fn, RNE, flush |f|<2^-6 to 0 (x,t ~ N(0,1)) ----
__device__ __forceinline__ unsigned f2e4m3(float f) {
  unsigned u = __float_as_uint(f);
  unsigned s = (u >> 24) & 0x80;
  unsigned mag = u & 0x7fffffffu;
  unsigned r = mag + 0x0007ffffu + ((mag >> 20) & 1u);  // RNE to 3 mantissa bits
  int e = (int)(r >> 23) - 127;
  if (e < -6) return s;                                 // flush tiny to zero
  unsigned m = (r >> 20) & 7u;
  return s | (unsigned)((e + 7) << 3) | m;
}

// ---- async global -> LDS, 16B per lane ----
__device__ __forceinline__ void async_copy16(const void* g, void* l) {
  __builtin_amdgcn_global_load_lds(
      (const __attribute__((address_space(1))) void*)g,
      (__attribute__((address_space(3))) void*)l, 16, 0, 0);
}

// ---- bf16 LDS slot swizzle (phi_b kernel, verified 0 conflicts) ----
__device__ __forceinline__ int swz_slot(int row, int slot) {
  return slot ^ ((row >> 1) & 3);
}

#define BARRIER __builtin_amdgcn_s_barrier()
#define LGKM0 do { asm volatile("s_waitcnt lgkmcnt(0)" ::: "memory"); \
                   __builtin_amdgcn_sched_barrier(0); } while (0)

// =====================================================================
// Kernel 1: stream x & target.
// fp8 outputs are written K-PERMUTED per 64-byte group:
//   out[g*64 + d*16 + h*8 + b] = in[g*64 + h*32 + d*8 + b]
// so one 16B chunk d = lane-d's {ks0, ks1} fragment pair for a K64 tile.
// bf16 Xb stays in original order (for phi_b). One wave per row.
// =====================================================================
__global__ __launch_bounds__(256)
void cast_rows_kernel(const float* __restrict__ x, const float* __restrict__ tgt,
                      unsigned short* __restrict__ Xb, unsigned char* __restrict__ Xf8,
                      unsigned char* __restrict__ Tf8,
                      float* __restrict__ xsq, float* __restrict__ tsq,
                      unsigned* __restrict__ keys) {
  const int gw = (blockIdx.x * 256 + threadIdx.x) >> 6;
  const int j = threadIdx.x & 63;
  // this lane's 8 output bytes are j*8..j*8+8 (permuted); source floats:
  const int base = (j >> 3) * 64 + (j & 1) * 32 + ((j >> 1) & 3) * 8;
  float s = 0.f;
  if (gw < N_PTS) {
    const float* src = x + (size_t)gw * DIM;
    float4 v0 = *(const float4*)(src + base);
    float4 v1 = *(const float4*)(src + base + 4);
    s = v0.x * v0.x + v0.y * v0.y + v0.z * v0.z + v0.w * v0.w +
        v1.x * v1.x + v1.y * v1.y + v1.z * v1.z + v1.w * v1.w;
    // bf16 at ORIGINAL positions
    unsigned short* db = Xb + (size_t)gw * DIM;
    ushort4 ob0, ob1;
    ob0.x = f2bf(v0.x); ob0.y = f2bf(v0.y); ob0.z = f2bf(v0.z); ob0.w = f2bf(v0.w);
    ob1.x = f2bf(v1.x); ob1.y = f2bf(v1.y); ob1.z = f2bf(v1.z); ob1.w = f2bf(v1.w);
    *(ushort4*)(db + base) = ob0;
    *(ushort4*)(db + base + 4) = ob1;
    // fp8 permuted: 8B at j*8
    unsigned long long p = (unsigned long long)f2e4m3(v0.x)
        | ((unsigned long long)f2e4m3(v0.y) << 8)
        | ((unsigned long long)f2e4m3(v0.z) << 16)
        | ((unsigned long long)f2e4m3(v0.w) << 24)
        | ((unsigned long long)f2e4m3(v1.x) << 32)
        | ((unsigned long long)f2e4m3(v1.y) << 40)
        | ((unsigned long long)f2e4m3(v1.z) << 48)
        | ((unsigned long long)f2e4m3(v1.w) << 56);
    *(unsigned long long*)(Xf8 + (size_t)gw * DIM + j * 8) = p;
#pragma unroll
    for (int m = 1; m <= 32; m <<= 1) s += __shfl_xor(s, m);
    if (j == 0) xsq[gw] = s;
  } else {
    const int tr = gw - N_PTS;
    const float* src = tgt + (size_t)tr * DIM;
    float4 v0 = *(const float4*)(src + base);
    float4 v1 = *(const float4*)(src + base + 4);
    s = v0.x * v0.x + v0.y * v0.y + v0.z * v0.z + v0.w * v0.w +
        v1.x * v1.x + v1.y * v1.y + v1.z * v1.z + v1.w * v1.w;
    unsigned long long p = (unsigned long long)f2e4m3(v0.x)
        | ((unsigned long long)f2e4m3(v0.y) << 8)
        | ((unsigned long long)f2e4m3(v0.z) << 16)
        | ((unsigned long long)f2e4m3(v0.w) << 24)
        | ((unsigned long long)f2e4m3(v1.x) << 32)
        | ((unsigned long long)f2e4m3(v1.y) << 40)
        | ((unsigned long long)f2e4m3(v1.z) << 48)
        | ((unsigned long long)f2e4m3(v1.w) << 56);
    *(unsigned long long*)(Tf8 + (size_t)tr * DIM + j * 8) = p;
#pragma unroll
    for (int m = 1; m <= 32; m <<= 1) s += __shfl_xor(s, m);
    if (j == 0) { tsq[tr] = s; keys[tr] = 0xFFFFFFFFu; }
  }
}

// =====================================================================
// Kernel 2: W [D][K] fp32 -> WbT [K][D] bf16 (transposed cast)
// =====================================================================
__global__ __launch_bounds__(256)
void prep_w_kernel(const float* __restrict__ W, unsigned short* __restrict__ WbT) {
  const int o = blockIdx.x * 256 + threadIdx.x;
  const int k = o >> 9, d = o & 511;
  WbT[o] = f2bf(W[d * KDIM + k]);
}

// =====================================================================
// Kernel 3: phi_b = logsumexp(Xb @ WbT^T) via bf16 MFMA (unchanged).
// =====================================================================
__global__ __launch_bounds__(256)
void phi_b_kernel(const short* __restrict__ Xb, const short* __restrict__ WbT,
                  float* __restrict__ phi_b) {
  __shared__ __align__(16) short As[BT * BKS];
  __shared__ __align__(16) short Bs[BT * BKS];
  __shared__ __align__(16) float lg[128][136];

  const int tid = threadIdx.x;
  const int wave = tid >> 6, lane = tid & 63;
  const int n0 = blockIdx.x * BT;
  const int srow = tid >> 2;
  const int sk8 = swz_slot(srow, tid & 3) * 8;
  const int wr = wave >> 1, wc = wave & 1;
  const int fr = lane & 15, g = lane >> 4;

  f32x4 acc[4][4] = {};
  for (int kt = 0; kt < DIM / BKS; ++kt) {
    const int k0 = kt * BKS;
    async_copy16(Xb + (size_t)(n0 + srow) * DIM + k0 + sk8, &As[wave * 512]);
    async_copy16(Xb + (size_t)(n0 + srow + 64) * DIM + k0 + sk8, &As[2048 + wave * 512]);
    async_copy16(WbT + (size_t)srow * DIM + k0 + sk8, &Bs[wave * 512]);
    async_copy16(WbT + (size_t)(srow + 64) * DIM + k0 + sk8, &Bs[2048 + wave * 512]);
    __syncthreads();
    short8 a[4], b[4];
#pragma unroll
    for (int i = 0; i < 4; ++i) {
      const int R = wr * 64 + i * 16 + fr;
      a[i] = *(const short8*)&As[R * BKS + swz_slot(R, g) * 8];
    }
#pragma unroll
    for (int j = 0; j < 4; ++j) {
      const int R = wc * 64 + j * 16 + fr;
      b[j] = *(const short8*)&Bs[R * BKS + swz_slot(R, g) * 8];
    }
#pragma unroll
    for (int i = 0; i < 4; ++i)
#pragma unroll
      for (int j = 0; j < 4; ++j)
        acc[i][j] = __builtin_amdgcn_mfma_f32_16x16x32_bf16(a[i], b[j], acc[i][j], 0, 0, 0);
    __syncthreads();
  }

  const int rq = g * 4;
#pragma unroll
  for (int i = 0; i < 4; ++i)
#pragma unroll
    for (int j = 0; j < 4; ++j)
#pragma unroll
      for (int q = 0; q < 4; ++q)
        lg[wr * 64 + i * 16 + rq + q][wc * 64 + j * 16 + fr] = acc[i][j][q];
  __syncthreads();

  const int row = tid >> 1, half = tid & 1;
  const float4* lr = (const float4*)(&lg[row][half * 64]);
  float mx = -3.4e38f;
#pragma unroll
  for (int c = 0; c < 16; ++c) {
    float4 v = lr[c];
    mx = fmaxf(mx, fmaxf(fmaxf(v.x, v.y), fmaxf(v.z, v.w)));
  }
  mx = fmaxf(mx, __shfl_xor(mx, 1));
  float s = 0.f;
#pragma unroll
  for (int c = 0; c < 16; ++c) {
    float4 v = lr[c];
    s += __expf(v.x - mx) + __expf(v.y - mx) + __expf(v.z - mx) + __expf(v.w - mx);
  }
  s += __shfl_xor(s, 1);
  if (half == 0) phi_b[n0 + row] = mx + logf(s);
}

// =====================================================================
// Kernel 4: fused fp8 MFMA GEMM + min epilogue.
// 256x256, BK=64, 8 waves. K-permuted fp8 rows -> ds_read_b128 gives
// {ks0,ks1} fragment pair; address pattern identical to the verified
// 0-conflict bf16 swizzle. 3 phases/K-tile:
//  P1 {8 reads -> Q1}, P2 {4 reads + stage B.h0 -> Q2},
//  P3 {stage B.h1,A.h0,A.h1 -> Q3+Q4 (32 MFMA) -> vmcnt(4)}.
// Ledger: 4 loads/wave/tile, 8 outstanding steady; vmcnt(4) end-P3
// retires tile t+1; tail vmcnt(0)/none. WAR: B drained end-P1,
// A drained end-P2 (lgkm0-before-barrier pattern).
// =====================================================================
__device__ __forceinline__ void stg8(const unsigned char* __restrict__ mat,
                                     int rowbase, int kbyte,
                                     unsigned char* lds8, int dst, int tid) {
  const int r = tid >> 2, d = tid & 3;
  async_copy16(mat + (size_t)(rowbase + r) * DIM + kbyte + ((d ^ ((r >> 1) & 3)) << 4),
               lds8 + dst + (tid >> 6) * 1024);
}

template <int VMC, bool STG>
__device__ __forceinline__ void ktile_f8(unsigned char* lds8, int bufo,
                                         const unsigned char* __restrict__ Xf,
                                         const unsigned char* __restrict__ Tf,
                                         int n0, int m0, int kb2, int tid,
                                         int aoff, int boff, f32x4 (&acc)[8][4]) {
  const unsigned char* Lb = lds8 + bufo;
  lpair A01[4], A45[4], B0[4];
  // ---- P1: read a0-3 + b0-3 (8 x b128); MFMA Q1 = (i0-3, ks0) ----
#pragma unroll
  for (int i = 0; i < 4; ++i) A01[i] = *(const lpair*)(Lb + aoff + i * 1024);
#pragma unroll
  for (int j = 0; j < 4; ++j) B0[j] = *(const lpair*)(Lb + boff + j * 1024);
  BARRIER; LGKM0;
  __builtin_amdgcn_s_setprio(1);
#pragma unroll
  for (int i = 0; i < 4; ++i)
#pragma unroll
    for (int j = 0; j < 4; ++j)
      acc[i][j] = __builtin_amdgcn_mfma_f32_16x16x32_fp8_fp8(
          A01[i][0], B0[j][0], acc[i][j], 0, 0, 0);
  __builtin_amdgcn_s_setprio(0);
  BARRIER;
  // ---- P2: read a4-7; stage B.h0(t+2); MFMA Q2 = (i4-7, ks0) ----
#pragma unroll
  for (int i = 0; i < 4; ++i) A45[i] = *(const lpair*)(Lb + aoff + (4 + i) * 1024);
  if (STG) stg8(Tf, m0, kb2, lds8, bufo + 16384, tid);
  BARRIER; LGKM0;
  __builtin_amdgcn_s_setprio(1);
#pragma unroll
  for (int i = 0; i < 4; ++i)
#pragma unroll
    for (int j = 0; j < 4; ++j)
      acc[4 + i][j] = __builtin_amdgcn_mfma_f32_16x16x32_fp8_fp8(
          A45[i][0], B0[j][0], acc[4 + i][j], 0, 0, 0);
  __builtin_amdgcn_s_setprio(0);
  BARRIER;
  // ---- P3: stage B.h1, A.h0, A.h1; MFMA Q3+Q4 (ks1); vmcnt ----
  if (STG) {
    stg8(Tf, m0 + 128, kb2, lds8, bufo + 16384 + 8192, tid);
    stg8(Xf, n0, kb2, lds8, bufo, tid);
    stg8(Xf, n0 + 128, kb2, lds8, bufo + 8192, tid);
  }
  BARRIER;
  __builtin_amdgcn_s_setprio(1);
#pragma unroll
  for (int i = 0; i < 4; ++i)
#pragma unroll
    for (int j = 0; j < 4; ++j)
      acc[i][j] = __builtin_amdgcn_mfma_f32_16x16x32_fp8_fp8(
          A01[i][1], B0[j][1], acc[i][j], 0, 0, 0);
#pragma unroll
  for (int i = 0; i < 4; ++i)
#pragma unroll
    for (int j = 0; j < 4; ++j)
      acc[4 + i][j] = __builtin_amdgcn_mfma_f32_16x16x32_fp8_fp8(
          A45[i][1], B0[j][1], acc[4 + i][j], 0, 0, 0);
  __builtin_amdgcn_s_setprio(0);
  if (VMC == 4) asm volatile("s_waitcnt vmcnt(4)" ::: "memory");
  else if (VMC == 0) asm volatile("s_waitcnt vmcnt(0)" ::: "memory");
  BARRIER;
}

__global__ __launch_bounds__(512, 2)
void gemm_min_kernel(const unsigned char* __restrict__ Xf, const unsigned char* __restrict__ Tf,
                     const float* __restrict__ phi_b, unsigned* __restrict__ keys) {
  __shared__ __align__(16) unsigned char lds8[65536];   // 64 KiB (2 x 32KB dbuf)

  const int tid = threadIdx.x;
  const int wave = tid >> 6, lane = tid & 63;
  const int wm = wave >> 2, wn = wave & 3;
  const int fr = lane & 15, g = lane >> 4;

  // 2D XCD chunking: 8 chunks of 8n x 16m tiles (~3MB working set / XCD L2)
  const int bid = blockIdx.x;
  const int xcd = bid & 7, idx = bid >> 3;
  const int nt = (xcd >> 1) * 8 + (idx >> 4);
  const int mt = (xcd & 1) * 16 + (idx & 15);
  const int n0 = nt * 256, m0 = mt * 256;

  // fragment byte offset: row*64 + (g ^ sw(row))*16  (verified-clean geometry)
  const int blk = ((g ^ ((fr >> 1) & 3)) << 4);
  const int aoff = (wm * 128 + fr) * 64 + blk;
  const int boff = 16384 + (wn * 64 + fr) * 64 + blk;

  // prologue: tile0 -> buf0, tile1 -> buf1 (8 loads); retire tile0's 4.
  stg8(Tf, m0, 0, lds8, 16384, tid);
  stg8(Tf, m0 + 128, 0, lds8, 16384 + 8192, tid);
  stg8(Xf, n0, 0, lds8, 0, tid);
  stg8(Xf, n0 + 128, 0, lds8, 8192, tid);
  stg8(Tf, m0, 64, lds8, 32768 + 16384, tid);
  stg8(Tf, m0 + 128, 64, lds8, 32768 + 16384 + 8192, tid);
  stg8(Xf, n0, 64, lds8, 32768, tid);
  stg8(Xf, n0 + 128, 64, lds8, 32768 + 8192, tid);
  asm volatile("s_waitcnt vmcnt(4)" ::: "memory");
  BARRIER;

  f32x4 acc[8][4] = {};
#pragma unroll 1
  for (int t = 0; t < 6; ++t)
    ktile_f8<4, true>(lds8, (t & 1) * 32768, Xf, Tf, n0, m0, (t + 2) * 64,
                      tid, aoff, boff, acc);
  ktile_f8<0, false>(lds8, 0, Xf, Tf, n0, m0, 0, tid, aoff, boff, acc);
  ktile_f8<-1, false>(lds8, 32768, Xf, Tf, n0, m0, 0, tid, aoff, boff, acc);

  // Epilogue: v = phi_b[n] - dot(n,m); per-column min over wave's 128 rows.
  // C/D layout (dtype-independent): col = lane&15, row = (lane>>4)*4 + q
  const int rq = g * 4;
  float mv[4] = {3.4e38f, 3.4e38f, 3.4e38f, 3.4e38f};
#pragma unroll
  for (int i = 0; i < 8; ++i) {
    float pb[4];
#pragma unroll
    for (int q = 0; q < 4; ++q) pb[q] = phi_b[n0 + wm * 128 + i * 16 + rq + q];
#pragma unroll
    for (int j = 0; j < 4; ++j)
#pragma unroll
      for (int q = 0; q < 4; ++q) mv[j] = fminf(mv[j], pb[q] - acc[i][j][q]);
  }
#pragma unroll
  for (int j = 0; j < 4; ++j) {
    float v = mv[j];
    v = fminf(v, __shfl_xor(v, 16));
    v = fminf(v, __shfl_xor(v, 32));
    if (g == 0) {
      atomicMin(&keys[m0 + wn * 64 + j * 16 + fr], fenc(v));
    }
  }
}

// =====================================================================
// Kernel 5: final reduce: mean(phi_k) + mean(phi_c). 1 block, 1024 thr.
// =====================================================================
__global__ __launch_bounds__(1024)
void finalize_kernel(const float* __restrict__ xsq, const float* __restrict__ phi_b,
                     const float* __restrict__ tsq, const unsigned* __restrict__ keys,
                     float* __restrict__ out) {
  const int t = threadIdx.x;
  double sk = 0.0, sc = 0.0;
  for (int n = t; n < N_PTS; n += 1024) sk += 0.5 * (double)xsq[n] - (double)phi_b[n];
  for (int m = t; m < M_PTS; m += 1024) sc += 0.5 * (double)tsq[m] + (double)fdec(keys[m]);
  const int lane = t & 63, wv = t >> 6;
#pragma unroll
  for (int m = 1; m <= 32; m <<= 1) {
    sk += __shfl_xor(sk, m);
    sc += __shfl_xor(sc, m);
  }
  __shared__ double pk[16], pc[16];
  if (lane == 0) { pk[wv] = sk; pc[wv] = sc; }
  __syncthreads();
  if (t == 0) {
    double a = 0.0, c = 0.0;
#pragma unroll
    for (int i = 0; i < 16; ++i) { a += pk[i]; c += pc[i]; }
    out[0] = (float)(a / N_PTS + c / M_PTS);
  }
}

// =====================================================================
extern "C" void kernel_launch(void* const* d_in, const int* in_sizes, int n_in,
                              void* d_out, int out_size, void* d_ws, size_t ws_size,
                              hipStream_t stream) {
  const float* x = (const float*)d_in[0];
  const float* tgt = (const float*)d_in[1];
  const float* W = (const float*)d_in[2];

  char* ws = (char*)d_ws;
  const size_t XB_BYTES = (size_t)N_PTS * DIM * 2;   // bf16 x (for phi_b)
  const size_t XF_BYTES = (size_t)N_PTS * DIM;       // fp8 x (K-permuted)
  const size_t TF_BYTES = (size_t)M_PTS * DIM;       // fp8 t (K-permuted)
  const size_t WT_BYTES = (size_t)KDIM * DIM * 2;
  unsigned short* Xb = (unsigned short*)ws;
  unsigned char* Xf8 = (unsigned char*)(ws + XB_BYTES);
  unsigned char* Tf8 = (unsigned char*)(ws + XB_BYTES + XF_BYTES);
  unsigned short* WbT = (unsigned short*)(ws + XB_BYTES + XF_BYTES + TF_BYTES);
  float* phi_b = (float*)(ws + XB_BYTES + XF_BYTES + TF_BYTES + WT_BYTES);
  float* xsq = phi_b + N_PTS;
  float* tsq = xsq + N_PTS;
  unsigned* keys = (unsigned*)(tsq + M_PTS);

  cast_rows_kernel<<<(N_PTS + M_PTS) / 4, 256, 0, stream>>>(x, tgt, Xb, Xf8, Tf8,
                                                            xsq, tsq, keys);
  prep_w_kernel<<<(KDIM * DIM) / 256, 256, 0, stream>>>(W, WbT);
  phi_b_kernel<<<N_PTS / BT, 256, 0, stream>>>((const short*)Xb, (const short*)WbT, phi_b);
  gemm_min_kernel<<<(N_PTS / 256) * (M_PTS / 256), 512, 0, stream>>>(Xf8, Tf8, phi_b, keys);
  finalize_kernel<<<1, 1024, 0, stream>>>(xsq, phi_b, tsq, keys, (float*)d_out);
}

// Round 10
// 75.750 us; speedup vs baseline: 1.3955x; 1.1558x over previous
//
#include <hip/hip_runtime.h>
#include <hip/hip_bf16.h>
#include <stdint.h>

typedef __attribute__((ext_vector_type(8))) short short8;
typedef __attribute__((ext_vector_type(4))) float f32x4;
typedef __attribute__((ext_vector_type(16))) float f32x16;
typedef __attribute__((ext_vector_type(4))) int i32x4;
typedef __attribute__((ext_vector_type(8))) int i32x8;

#define N_PTS 8192
#define M_PTS 8192
#define DIM   512
#define KDIM  128
#define BT    128   // phi_b tile
#define BKS   32

// ---- float <-> order-preserving uint key (for atomicMin on float) ----
__device__ __forceinline__ unsigned fenc(float f) {
  unsigned u = __float_as_uint(f);
  return (u & 0x80000000u) ? ~u : (u | 0x80000000u);
}
__device__ __forceinline__ float fdec(unsigned k) {
  unsigned u = (k & 0x80000000u) ? (k ^ 0x80000000u) : ~k;
  return __uint_as_float(u);
}

__device__ __forceinline__ unsigned short f2bf(float f) {
  union { __hip_bfloat16 h; unsigned short u; } c;
  c.h = __float2bfloat16(f);
  return c.u;
}

// ---- float -> OCP e4m3fn, RNE, flush |f|<2^-6 to 0 (x,t ~ N(0,1)) ----
__device__ __forceinline__ unsigned f2e4m3(float f) {
  unsigned u = __float_as_uint(f);
  unsigned s = (u >> 24) & 0x80;
  unsigned mag = u & 0x7fffffffu;
  unsigned r = mag + 0x0007ffffu + ((mag >> 20) & 1u);  // RNE to 3 mantissa bits
  int e = (int)(r >> 23) - 127;
  if (e < -6) return s;                                 // flush tiny to zero
  unsigned m = (r >> 20) & 7u;
  return s | (unsigned)((e + 7) << 3) | m;
}

// ---- async global -> LDS, 16B per lane ----
__device__ __forceinline__ void async_copy16(const void* g, void* l) {
  __builtin_amdgcn_global_load_lds(
      (const __attribute__((address_space(1))) void*)g,
      (__attribute__((address_space(3))) void*)l, 16, 0, 0);
}

// ---- bf16 LDS slot swizzle (phi_b kernel, verified 0 conflicts) ----
__device__ __forceinline__ int swz_slot(int row, int slot) {
  return slot ^ ((row >> 1) & 3);
}

#define BARRIER __builtin_amdgcn_s_barrier()
#define LGKM0 do { asm volatile("s_waitcnt lgkmcnt(0)" ::: "memory"); \
                   __builtin_amdgcn_sched_barrier(0); } while (0)

// =====================================================================
// Kernel 1: prep-all. Blocks < 4096: one wave per row of x/target:
// bf16 cast (x only), fp8 e4m3 cast (plain row order), sumsq, key init.
// Blocks >= 4096: W [D][K] fp32 -> WbT [K][D] bf16 transpose-cast.
// =====================================================================
__global__ __launch_bounds__(256)
void prep_all_kernel(const float* __restrict__ x, const float* __restrict__ tgt,
                     const float* __restrict__ W,
                     unsigned short* __restrict__ Xb, unsigned char* __restrict__ Xf8,
                     unsigned char* __restrict__ Tf8, unsigned short* __restrict__ WbT,
                     float* __restrict__ xsq, float* __restrict__ tsq,
                     unsigned* __restrict__ keys) {
  const int bid = blockIdx.x;
  const int tid = threadIdx.x;
  if (bid >= (N_PTS + M_PTS) / 4) {
    const int o = (bid - (N_PTS + M_PTS) / 4) * 256 + tid;  // 0..65535
    const int k = o >> 9, d = o & 511;
    WbT[o] = f2bf(W[d * KDIM + k]);
    return;
  }
  const int gw = (bid * 256 + tid) >> 6;
  const int j = tid & 63;
  float s;
  if (gw < N_PTS) {
    const float* src = x + (size_t)gw * DIM + j * 8;
    float4 v0 = *(const float4*)src;
    float4 v1 = *(const float4*)(src + 4);
    s = v0.x * v0.x + v0.y * v0.y + v0.z * v0.z + v0.w * v0.w +
        v1.x * v1.x + v1.y * v1.y + v1.z * v1.z + v1.w * v1.w;
    unsigned short* db = Xb + (size_t)gw * DIM + j * 8;
    ushort4 ob0, ob1;
    ob0.x = f2bf(v0.x); ob0.y = f2bf(v0.y); ob0.z = f2bf(v0.z); ob0.w = f2bf(v0.w);
    ob1.x = f2bf(v1.x); ob1.y = f2bf(v1.y); ob1.z = f2bf(v1.z); ob1.w = f2bf(v1.w);
    *(ushort4*)db = ob0;
    *(ushort4*)(db + 4) = ob1;
    unsigned long long p = (unsigned long long)f2e4m3(v0.x)
        | ((unsigned long long)f2e4m3(v0.y) << 8)
        | ((unsigned long long)f2e4m3(v0.z) << 16)
        | ((unsigned long long)f2e4m3(v0.w) << 24)
        | ((unsigned long long)f2e4m3(v1.x) << 32)
        | ((unsigned long long)f2e4m3(v1.y) << 40)
        | ((unsigned long long)f2e4m3(v1.z) << 48)
        | ((unsigned long long)f2e4m3(v1.w) << 56);
    *(unsigned long long*)(Xf8 + (size_t)gw * DIM + j * 8) = p;
#pragma unroll
    for (int m = 1; m <= 32; m <<= 1) s += __shfl_xor(s, m);
    if (j == 0) xsq[gw] = s;
  } else {
    const int tr = gw - N_PTS;
    const float* src = tgt + (size_t)tr * DIM + j * 8;
    float4 v0 = *(const float4*)src;
    float4 v1 = *(const float4*)(src + 4);
    s = v0.x * v0.x + v0.y * v0.y + v0.z * v0.z + v0.w * v0.w +
        v1.x * v1.x + v1.y * v1.y + v1.z * v1.z + v1.w * v1.w;
    unsigned long long p = (unsigned long long)f2e4m3(v0.x)
        | ((unsigned long long)f2e4m3(v0.y) << 8)
        | ((unsigned long long)f2e4m3(v0.z) << 16)
        | ((unsigned long long)f2e4m3(v0.w) << 24)
        | ((unsigned long long)f2e4m3(v1.x) << 32)
        | ((unsigned long long)f2e4m3(v1.y) << 40)
        | ((unsigned long long)f2e4m3(v1.z) << 48)
        | ((unsigned long long)f2e4m3(v1.w) << 56);
    *(unsigned long long*)(Tf8 + (size_t)tr * DIM + j * 8) = p;
#pragma unroll
    for (int m = 1; m <= 32; m <<= 1) s += __shfl_xor(s, m);
    if (j == 0) { tsq[tr] = s; keys[tr] = 0xFFFFFFFFu; }
  }
}

// =====================================================================
// Kernel 2: phi_b = logsumexp(Xb @ WbT^T) via bf16 MFMA (unchanged).
// =====================================================================
__global__ __launch_bounds__(256)
void phi_b_kernel(const short* __restrict__ Xb, const short* __restrict__ WbT,
                  float* __restrict__ phi_b) {
  __shared__ __align__(16) short As[BT * BKS];
  __shared__ __align__(16) short Bs[BT * BKS];
  __shared__ __align__(16) float lg[128][136];

  const int tid = threadIdx.x;
  const int wave = tid >> 6, lane = tid & 63;
  const int n0 = blockIdx.x * BT;
  const int srow = tid >> 2;
  const int sk8 = swz_slot(srow, tid & 3) * 8;
  const int wr = wave >> 1, wc = wave & 1;
  const int fr = lane & 15, g = lane >> 4;

  f32x4 acc[4][4] = {};
  for (int kt = 0; kt < DIM / BKS; ++kt) {
    const int k0 = kt * BKS;
    async_copy16(Xb + (size_t)(n0 + srow) * DIM + k0 + sk8, &As[wave * 512]);
    async_copy16(Xb + (size_t)(n0 + srow + 64) * DIM + k0 + sk8, &As[2048 + wave * 512]);
    async_copy16(WbT + (size_t)srow * DIM + k0 + sk8, &Bs[wave * 512]);
    async_copy16(WbT + (size_t)(srow + 64) * DIM + k0 + sk8, &Bs[2048 + wave * 512]);
    __syncthreads();
    short8 a[4], b[4];
#pragma unroll
    for (int i = 0; i < 4; ++i) {
      const int R = wr * 64 + i * 16 + fr;
      a[i] = *(const short8*)&As[R * BKS + swz_slot(R, g) * 8];
    }
#pragma unroll
    for (int j = 0; j < 4; ++j) {
      const int R = wc * 64 + j * 16 + fr;
      b[j] = *(const short8*)&Bs[R * BKS + swz_slot(R, g) * 8];
    }
#pragma unroll
    for (int i = 0; i < 4; ++i)
#pragma unroll
      for (int j = 0; j < 4; ++j)
        acc[i][j] = __builtin_amdgcn_mfma_f32_16x16x32_bf16(a[i], b[j], acc[i][j], 0, 0, 0);
    __syncthreads();
  }

  const int rq = g * 4;
#pragma unroll
  for (int i = 0; i < 4; ++i)
#pragma unroll
    for (int j = 0; j < 4; ++j)
#pragma unroll
      for (int q = 0; q < 4; ++q)
        lg[wr * 64 + i * 16 + rq + q][wc * 64 + j * 16 + fr] = acc[i][j][q];
  __syncthreads();

  const int row = tid >> 1, half = tid & 1;
  const float4* lr = (const float4*)(&lg[row][half * 64]);
  float mx = -3.4e38f;
#pragma unroll
  for (int c = 0; c < 16; ++c) {
    float4 v = lr[c];
    mx = fmaxf(mx, fmaxf(fmaxf(v.x, v.y), fmaxf(v.z, v.w)));
  }
  mx = fmaxf(mx, __shfl_xor(mx, 1));
  float s = 0.f;
#pragma unroll
  for (int c = 0; c < 16; ++c) {
    float4 v = lr[c];
    s += __expf(v.x - mx) + __expf(v.y - mx) + __expf(v.z - mx) + __expf(v.w - mx);
  }
  s += __shfl_xor(s, 1);
  if (half == 0) phi_b[n0 + row] = mx + logf(s);
}

// =====================================================================
// Kernel 3: fused MX-fp8 (scale=1.0) MFMA GEMM + min epilogue.
// 256x256, BK=64, 8 waves (2Mx4N), mfma_scale_f32_32x32x64_f8f6f4.
// LDS 64KB = 2 dbuf x {A[256][64B] @0, B @16384}. Chunk-XOR swizzle
// (d ^ ((r>>1)&3)) via pre-swizzled global source; fragment = 32
// contiguous K-bytes per lane read as 2 x ds_read_b128 (off, off^16).
// 2 phases/K64: P1 {12 reads -> barrier -> lgkm0 -> 4 MFMA (j=0)},
// P2 {stage 4 halves (t+2) -> 4 MFMA (j=1) -> vmcnt(4) -> barrier}.
// Ledger: 4 loads/wave/tile; vmcnt(4) end-P2 retires tile t+1; WAR
// closed (P1-end barrier drains all reads before P2 stages).
// =====================================================================
__device__ __forceinline__ void stg8(const unsigned char* __restrict__ mat,
                                     int rowbase, int kbyte,
                                     unsigned char* lds8, int dst, int tid) {
  const int r = tid >> 2, d = tid & 3;
  async_copy16(mat + (size_t)(rowbase + r) * DIM + kbyte + ((d ^ ((r >> 1) & 3)) << 4),
               lds8 + dst + (tid >> 6) * 1024);
}

__device__ __forceinline__ i32x8 ldfrag(const unsigned char* lds, int off) {
  i32x4 lo = *(const i32x4*)(lds + off);         // source chunk 2h  (k .. k+15)
  i32x4 hi = *(const i32x4*)(lds + (off ^ 16));  // source chunk 2h+1 (k+16..k+31)
  return __builtin_shufflevector(lo, hi, 0, 1, 2, 3, 4, 5, 6, 7);
}

__device__ __forceinline__ f32x16 mfma_mx(i32x8 a, i32x8 b, f32x16 c) {
  // cbsz=0 (A fp8 e4m3), blgp=0 (B fp8), scales = e8m0 127 -> 1.0
  return __builtin_amdgcn_mfma_scale_f32_32x32x64_f8f6f4(a, b, c, 0, 0,
                                                         0, 0x7F, 0, 0x7F);
}

template <int VMC, bool STG>
__device__ __forceinline__ void ktile_mx(unsigned char* lds8, int bufo,
                                         const unsigned char* __restrict__ Xf,
                                         const unsigned char* __restrict__ Tf,
                                         int n0, int m0, int kb2, int tid,
                                         int aoff, int boff, f32x16 (&acc)[4][2]) {
  const unsigned char* L = lds8 + bufo;
  i32x8 fa[4], fb[2];
  // ---- P1: 12 x ds_read_b128; MFMA column j=0 ----
#pragma unroll
  for (int i = 0; i < 4; ++i) fa[i] = ldfrag(L, aoff + i * 2048);
#pragma unroll
  for (int j = 0; j < 2; ++j) fb[j] = ldfrag(L, boff + j * 2048);
  BARRIER; LGKM0;
  __builtin_amdgcn_s_setprio(1);
#pragma unroll
  for (int i = 0; i < 4; ++i) acc[i][0] = mfma_mx(fa[i], fb[0], acc[i][0]);
  __builtin_amdgcn_s_setprio(0);
  BARRIER;
  // ---- P2: stage tile t+2 (same buffer, reads drained); MFMA j=1 ----
  if (STG) {
    stg8(Tf, m0, kb2, lds8, bufo + 16384, tid);
    stg8(Tf, m0 + 128, kb2, lds8, bufo + 16384 + 8192, tid);
    stg8(Xf, n0, kb2, lds8, bufo, tid);
    stg8(Xf, n0 + 128, kb2, lds8, bufo + 8192, tid);
  }
  __builtin_amdgcn_s_setprio(1);
#pragma unroll
  for (int i = 0; i < 4; ++i) acc[i][1] = mfma_mx(fa[i], fb[1], acc[i][1]);
  __builtin_amdgcn_s_setprio(0);
  if (VMC == 4) asm volatile("s_waitcnt vmcnt(4)" ::: "memory");
  else if (VMC == 0) asm volatile("s_waitcnt vmcnt(0)" ::: "memory");
  BARRIER;
}

__global__ __launch_bounds__(512, 2)
void gemm_min_kernel(const unsigned char* __restrict__ Xf, const unsigned char* __restrict__ Tf,
                     const float* __restrict__ phi_b, unsigned* __restrict__ keys) {
  __shared__ __align__(16) unsigned char lds8[65536];   // 64 KiB (2 x 32KB dbuf)

  const int tid = threadIdx.x;
  const int wave = tid >> 6, lane = tid & 63;
  const int wm = wave >> 2, wn = wave & 3;
  const int fr5 = lane & 31, h = lane >> 5;

  // 2D XCD chunking: 8 chunks of 8n x 16m tiles (~3MB working set / XCD L2)
  const int bid = blockIdx.x;
  const int xcd = bid & 7, idx = bid >> 3;
  const int nt = (xcd >> 1) * 8 + (idx >> 4);
  const int mt = (xcd & 1) * 16 + (idx & 15);
  const int n0 = nt * 256, m0 = mt * 256;

  // fragment byte offsets: row*64 + ((2h ^ key)<<4), key=(fr5>>1)&3 == (row>>1)&3
  const int key = (fr5 >> 1) & 3;
  const int aoff = (wm * 128 + fr5) * 64 + (((h << 1) ^ key) << 4);
  const int boff = 16384 + (wn * 64 + fr5) * 64 + (((h << 1) ^ key) << 4);

  // prologue: tile0 -> buf0, tile1 -> buf1 (8 loads); retire tile0's 4.
  stg8(Tf, m0, 0, lds8, 16384, tid);
  stg8(Tf, m0 + 128, 0, lds8, 16384 + 8192, tid);
  stg8(Xf, n0, 0, lds8, 0, tid);
  stg8(Xf, n0 + 128, 0, lds8, 8192, tid);
  stg8(Tf, m0, 64, lds8, 32768 + 16384, tid);
  stg8(Tf, m0 + 128, 64, lds8, 32768 + 16384 + 8192, tid);
  stg8(Xf, n0, 64, lds8, 32768, tid);
  stg8(Xf, n0 + 128, 64, lds8, 32768 + 8192, tid);
  asm volatile("s_waitcnt vmcnt(4)" ::: "memory");
  BARRIER;

  f32x16 acc[4][2] = {};
#pragma unroll 1
  for (int t = 0; t < 6; ++t)
    ktile_mx<4, true>(lds8, (t & 1) * 32768, Xf, Tf, n0, m0, (t + 2) * 64,
                      tid, aoff, boff, acc);
  ktile_mx<0, false>(lds8, 0, Xf, Tf, n0, m0, 0, tid, aoff, boff, acc);
  ktile_mx<-1, false>(lds8, 32768, Xf, Tf, n0, m0, 0, tid, aoff, boff, acc);

  // Epilogue: v = phi_b[n] - dot; min over the wave's 128 rows per column.
  // 32x32 C/D layout (m74/m101): col = lane&31, row = (q&3)+8*(q>>2)+4*h
  float mv0 = 3.4e38f, mv1 = 3.4e38f;
#pragma unroll
  for (int i = 0; i < 4; ++i) {
    float pb[16];
#pragma unroll
    for (int q = 0; q < 16; ++q)
      pb[q] = phi_b[n0 + wm * 128 + i * 32 + (q & 3) + 8 * (q >> 2) + 4 * h];
#pragma unroll
    for (int q = 0; q < 16; ++q) {
      mv0 = fminf(mv0, pb[q] - acc[i][0][q]);
      mv1 = fminf(mv1, pb[q] - acc[i][1][q]);
    }
  }
  mv0 = fminf(mv0, __shfl_xor(mv0, 32));
  mv1 = fminf(mv1, __shfl_xor(mv1, 32));
  if (h == 0) {
    atomicMin(&keys[m0 + wn * 64 + fr5], fenc(mv0));
    atomicMin(&keys[m0 + wn * 64 + 32 + fr5], fenc(mv1));
  }
}

// =====================================================================
// Kernel 4: final reduce: mean(phi_k) + mean(phi_c). 1 block, 1024 thr.
// =====================================================================
__global__ __launch_bounds__(1024)
void finalize_kernel(const float* __restrict__ xsq, const float* __restrict__ phi_b,
                     const float* __restrict__ tsq, const unsigned* __restrict__ keys,
                     float* __restrict__ out) {
  const int t = threadIdx.x;
  double sk = 0.0, sc = 0.0;
  for (int n = t; n < N_PTS; n += 1024) sk += 0.5 * (double)xsq[n] - (double)phi_b[n];
  for (int m = t; m < M_PTS; m += 1024) sc += 0.5 * (double)tsq[m] + (double)fdec(keys[m]);
  const int lane = t & 63, wv = t >> 6;
#pragma unroll
  for (int m = 1; m <= 32; m <<= 1) {
    sk += __shfl_xor(sk, m);
    sc += __shfl_xor(sc, m);
  }
  __shared__ double pk[16], pc[16];
  if (lane == 0) { pk[wv] = sk; pc[wv] = sc; }
  __syncthreads();
  if (t == 0) {
    double a = 0.0, c = 0.0;
#pragma unroll
    for (int i = 0; i < 16; ++i) { a += pk[i]; c += pc[i]; }
    out[0] = (float)(a / N_PTS + c / M_PTS);
  }
}

// =====================================================================
extern "C" void kernel_launch(void* const* d_in, const int* in_sizes, int n_in,
                              void* d_out, int out_size, void* d_ws, size_t ws_size,
                              hipStream_t stream) {
  const float* x = (const float*)d_in[0];
  const float* tgt = (const float*)d_in[1];
  const float* W = (const float*)d_in[2];

  char* ws = (char*)d_ws;
  const size_t XB_BYTES = (size_t)N_PTS * DIM * 2;   // bf16 x (for phi_b)
  const size_t XF_BYTES = (size_t)N_PTS * DIM;       // fp8 x (plain row order)
  const size_t TF_BYTES = (size_t)M_PTS * DIM;       // fp8 t
  const size_t WT_BYTES = (size_t)KDIM * DIM * 2;
  unsigned short* Xb = (unsigned short*)ws;
  unsigned char* Xf8 = (unsigned char*)(ws + XB_BYTES);
  unsigned char* Tf8 = (unsigned char*)(ws + XB_BYTES + XF_BYTES);
  unsigned short* WbT = (unsigned short*)(ws + XB_BYTES + XF_BYTES + TF_BYTES);
  float* phi_b = (float*)(ws + XB_BYTES + XF_BYTES + TF_BYTES + WT_BYTES);
  float* xsq = phi_b + N_PTS;
  float* tsq = xsq + N_PTS;
  unsigned* keys = (unsigned*)(tsq + M_PTS);

  const int prep_blocks = (N_PTS + M_PTS) / 4 + (KDIM * DIM) / 256;
  prep_all_kernel<<<prep_blocks, 256, 0, stream>>>(x, tgt, W, Xb, Xf8, Tf8, WbT,
                                                   xsq, tsq, keys);
  phi_b_kernel<<<N_PTS / BT, 256, 0, stream>>>((const short*)Xb, (const short*)WbT, phi_b);
  gemm_min_kernel<<<(N_PTS / 256) * (M_PTS / 256), 512, 0, stream>>>(Xf8, Tf8, phi_b, keys);
  finalize_kernel<<<1, 1024, 0, stream>>>(xsq, phi_b, tsq, keys, (float*)d_out);
}

// Round 11
// 71.769 us; speedup vs baseline: 1.4729x; 1.0555x over previous
//
#include <hip/hip_runtime.h>
#include <hip/hip_bf16.h>
#include <stdint.h>

typedef __attribute__((ext_vector_type(8))) short short8;
typedef __attribute__((ext_vector_type(4))) float f32x4;
typedef __attribute__((ext_vector_type(16))) float f32x16;
typedef __attribute__((ext_vector_type(4))) int i32x4;
typedef __attribute__((ext_vector_type(8))) int i32x8;

#define N_PTS 8192
#define M_PTS 8192
#define DIM   512
#define KDIM  128
#define BT    128   // phi_b tile
#define BKS   32

// ---- float <-> order-preserving uint key (for atomicMin on float) ----
__device__ __forceinline__ unsigned fenc(float f) {
  unsigned u = __float_as_uint(f);
  return (u & 0x80000000u) ? ~u : (u | 0x80000000u);
}
__device__ __forceinline__ float fdec(unsigned k) {
  unsigned u = (k & 0x80000000u) ? (k ^ 0x80000000u) : ~k;
  return __uint_as_float(u);
}

__device__ __forceinline__ unsigned short f2bf(float f) {
  union { __hip_bfloat16 h; unsigned short u; } c;
  c.h = __float2bfloat16(f);
  return c.u;
}

// ---- float -> OCP e4m3fn, RNE, flush |f|<2^-6 to 0 (x,t ~ N(0,1)) ----
__device__ __forceinline__ unsigned f2e4m3(float f) {
  unsigned u = __float_as_uint(f);
  unsigned s = (u >> 24) & 0x80;
  unsigned mag = u & 0x7fffffffu;
  unsigned r = mag + 0x0007ffffu + ((mag >> 20) & 1u);  // RNE to 3 mantissa bits
  int e = (int)(r >> 23) - 127;
  if (e < -6) return s;                                 // flush tiny to zero
  unsigned m = (r >> 20) & 7u;
  return s | (unsigned)((e + 7) << 3) | m;
}

// ---- async global -> LDS, 16B per lane ----
__device__ __forceinline__ void async_copy16(const void* g, void* l) {
  __builtin_amdgcn_global_load_lds(
      (const __attribute__((address_space(1))) void*)g,
      (__attribute__((address_space(3))) void*)l, 16, 0, 0);
}

// ---- bf16 LDS slot swizzle (phi_b kernel, verified 0 conflicts) ----
__device__ __forceinline__ int swz_slot(int row, int slot) {
  return slot ^ ((row >> 1) & 3);
}

#define BARRIER __builtin_amdgcn_s_barrier()

// =====================================================================
// Kernel 1: prep-all. Blocks < 4096: one wave per row of x/target:
// x -> Xb(bf16) + Xf8(e4m3 plain rows) + xsq; target -> TfT (e4m3,
// FRAGMENT-MAJOR [kt][8192][64B]) + tsq + key init.
// Blocks >= 4096: W [D][K] fp32 -> WbT [K][D] bf16 transpose-cast.
// =====================================================================
__global__ __launch_bounds__(256)
void prep_all_kernel(const float* __restrict__ x, const float* __restrict__ tgt,
                     const float* __restrict__ W,
                     unsigned short* __restrict__ Xb, unsigned char* __restrict__ Xf8,
                     unsigned char* __restrict__ TfT, unsigned short* __restrict__ WbT,
                     float* __restrict__ xsq, float* __restrict__ tsq,
                     unsigned* __restrict__ keys) {
  const int bid = blockIdx.x;
  const int tid = threadIdx.x;
  if (bid >= (N_PTS + M_PTS) / 4) {
    const int o = (bid - (N_PTS + M_PTS) / 4) * 256 + tid;  // 0..65535
    const int k = o >> 9, d = o & 511;
    WbT[o] = f2bf(W[d * KDIM + k]);
    return;
  }
  const int gw = (bid * 256 + tid) >> 6;
  const int j = tid & 63;
  float s;
  if (gw < N_PTS) {
    const float* src = x + (size_t)gw * DIM + j * 8;
    float4 v0 = *(const float4*)src;
    float4 v1 = *(const float4*)(src + 4);
    s = v0.x * v0.x + v0.y * v0.y + v0.z * v0.z + v0.w * v0.w +
        v1.x * v1.x + v1.y * v1.y + v1.z * v1.z + v1.w * v1.w;
    unsigned short* db = Xb + (size_t)gw * DIM + j * 8;
    ushort4 ob0, ob1;
    ob0.x = f2bf(v0.x); ob0.y = f2bf(v0.y); ob0.z = f2bf(v0.z); ob0.w = f2bf(v0.w);
    ob1.x = f2bf(v1.x); ob1.y = f2bf(v1.y); ob1.z = f2bf(v1.z); ob1.w = f2bf(v1.w);
    *(ushort4*)db = ob0;
    *(ushort4*)(db + 4) = ob1;
    unsigned long long p = (unsigned long long)f2e4m3(v0.x)
        | ((unsigned long long)f2e4m3(v0.y) << 8)
        | ((unsigned long long)f2e4m3(v0.z) << 16)
        | ((unsigned long long)f2e4m3(v0.w) << 24)
        | ((unsigned long long)f2e4m3(v1.x) << 32)
        | ((unsigned long long)f2e4m3(v1.y) << 40)
        | ((unsigned long long)f2e4m3(v1.z) << 48)
        | ((unsigned long long)f2e4m3(v1.w) << 56);
    *(unsigned long long*)(Xf8 + (size_t)gw * DIM + j * 8) = p;
#pragma unroll
    for (int m = 1; m <= 32; m <<= 1) s += __shfl_xor(s, m);
    if (j == 0) xsq[gw] = s;
  } else {
    const int tr = gw - N_PTS;
    const float* src = tgt + (size_t)tr * DIM + j * 8;
    float4 v0 = *(const float4*)src;
    float4 v1 = *(const float4*)(src + 4);
    s = v0.x * v0.x + v0.y * v0.y + v0.z * v0.z + v0.w * v0.w +
        v1.x * v1.x + v1.y * v1.y + v1.z * v1.z + v1.w * v1.w;
    unsigned long long p = (unsigned long long)f2e4m3(v0.x)
        | ((unsigned long long)f2e4m3(v0.y) << 8)
        | ((unsigned long long)f2e4m3(v0.z) << 16)
        | ((unsigned long long)f2e4m3(v0.w) << 24)
        | ((unsigned long long)f2e4m3(v1.x) << 32)
        | ((unsigned long long)f2e4m3(v1.y) << 40)
        | ((unsigned long long)f2e4m3(v1.z) << 48)
        | ((unsigned long long)f2e4m3(v1.w) << 56);
    // fragment-major: [kt = j>>3][row tr][byte (j&7)*8]
    *(unsigned long long*)(TfT + ((size_t)(j >> 3) * M_PTS + tr) * 64 + (j & 7) * 8) = p;
#pragma unroll
    for (int m = 1; m <= 32; m <<= 1) s += __shfl_xor(s, m);
    if (j == 0) { tsq[tr] = s; keys[tr] = 0xFFFFFFFFu; }
  }
}

// =====================================================================
// Kernel 2: phi_b = logsumexp(Xb @ WbT^T) via bf16 MFMA (unchanged).
// =====================================================================
__global__ __launch_bounds__(256)
void phi_b_kernel(const short* __restrict__ Xb, const short* __restrict__ WbT,
                  float* __restrict__ phi_b) {
  __shared__ __align__(16) short As[BT * BKS];
  __shared__ __align__(16) short Bs[BT * BKS];
  __shared__ __align__(16) float lg[128][136];

  const int tid = threadIdx.x;
  const int wave = tid >> 6, lane = tid & 63;
  const int n0 = blockIdx.x * BT;
  const int srow = tid >> 2;
  const int sk8 = swz_slot(srow, tid & 3) * 8;
  const int wr = wave >> 1, wc = wave & 1;
  const int fr = lane & 15, g = lane >> 4;

  f32x4 acc[4][4] = {};
  for (int kt = 0; kt < DIM / BKS; ++kt) {
    const int k0 = kt * BKS;
    async_copy16(Xb + (size_t)(n0 + srow) * DIM + k0 + sk8, &As[wave * 512]);
    async_copy16(Xb + (size_t)(n0 + srow + 64) * DIM + k0 + sk8, &As[2048 + wave * 512]);
    async_copy16(WbT + (size_t)srow * DIM + k0 + sk8, &Bs[wave * 512]);
    async_copy16(WbT + (size_t)(srow + 64) * DIM + k0 + sk8, &Bs[2048 + wave * 512]);
    __syncthreads();
    short8 a[4], b[4];
#pragma unroll
    for (int i = 0; i < 4; ++i) {
      const int R = wr * 64 + i * 16 + fr;
      a[i] = *(const short8*)&As[R * BKS + swz_slot(R, g) * 8];
    }
#pragma unroll
    for (int j = 0; j < 4; ++j) {
      const int R = wc * 64 + j * 16 + fr;
      b[j] = *(const short8*)&Bs[R * BKS + swz_slot(R, g) * 8];
    }
#pragma unroll
    for (int i = 0; i < 4; ++i)
#pragma unroll
      for (int j = 0; j < 4; ++j)
        acc[i][j] = __builtin_amdgcn_mfma_f32_16x16x32_bf16(a[i], b[j], acc[i][j], 0, 0, 0);
    __syncthreads();
  }

  const int rq = g * 4;
#pragma unroll
  for (int i = 0; i < 4; ++i)
#pragma unroll
    for (int j = 0; j < 4; ++j)
#pragma unroll
      for (int q = 0; q < 4; ++q)
        lg[wr * 64 + i * 16 + rq + q][wc * 64 + j * 16 + fr] = acc[i][j][q];
  __syncthreads();

  const int row = tid >> 1, half = tid & 1;
  const float4* lr = (const float4*)(&lg[row][half * 64]);
  float mx = -3.4e38f;
#pragma unroll
  for (int c = 0; c < 16; ++c) {
    float4 v = lr[c];
    mx = fmaxf(mx, fmaxf(fmaxf(v.x, v.y), fmaxf(v.z, v.w)));
  }
  mx = fmaxf(mx, __shfl_xor(mx, 1));
  float s = 0.f;
#pragma unroll
  for (int c = 0; c < 16; ++c) {
    float4 v = lr[c];
    s += __expf(v.x - mx) + __expf(v.y - mx) + __expf(v.z - mx) + __expf(v.w - mx);
  }
  s += __shfl_xor(s, 1);
  if (half == 0) phi_b[n0 + row] = mx + logf(s);
}

// =====================================================================
// Kernel 3: fused MX-fp8 GEMM + min epilogue — B DIRECT FROM L2.
// 256x256, BK=64, 8 waves (2Mx4N). A staged in 3x16KB LDS buffers
// (stage-2-ahead, stg into buf[(t+2)%3] whose readers drained at
// barrier(t-1)); B loaded straight to regs from fragment-major TfT
// (coalesced 2KB windows, L2-hot via XCD chunking), double-buffered
// via call-site-alternated reg sets. ONE barrier per K64 tile; MFMA
// waits only compiler-counted lgkm on same-tile A reads.
// vmcnt ledger (6 VMEM issues/tile = 4 B-frag + 2 A-stage):
// vmcnt(6) at tile end keeps this tile's issues, retires prior tile's
// (incl. S(t+1) needed next tile). Prologue S0,S1 + vmcnt(0);
// t6 vmcnt(4); t7 none.
// =====================================================================
__device__ __forceinline__ void stgA(const unsigned char* __restrict__ mat,
                                     int rowbase, int kbyte,
                                     unsigned char* dst, int tid) {
  const int r = tid >> 2, d = tid & 3;
  async_copy16(mat + (size_t)(rowbase + r) * DIM + kbyte + ((d ^ ((r >> 1) & 3)) << 4),
               dst + (tid >> 6) * 1024);
}

__device__ __forceinline__ i32x8 ld2x16(const unsigned char* p0, const unsigned char* p1) {
  i32x4 lo = *(const i32x4*)p0;
  i32x4 hi = *(const i32x4*)p1;
  return __builtin_shufflevector(lo, hi, 0, 1, 2, 3, 4, 5, 6, 7);
}

__device__ __forceinline__ f32x16 mfma_mx(i32x8 a, i32x8 b, f32x16 c) {
  return __builtin_amdgcn_mfma_scale_f32_32x32x64_f8f6f4(a, b, c, 0, 0,
                                                         0, 0x7F, 0, 0x7F);
}

// VMC: vmcnt at tile end (6 steady, 4 = t6, -1 = none). STG: stage S(t+2).
// LDB: load fbn = B frags of tile t+1. BAR: trailing barrier.
template <int VMC, bool STG, bool LDB, bool BAR>
__device__ __forceinline__ void ktile(const unsigned char* Abuf, unsigned char* Sbuf,
                                      const unsigned char* __restrict__ Xf,
                                      const unsigned char* __restrict__ Bnx,
                                      int n0, int kstage, int tid, int aoff,
                                      i32x8 (&fb)[2], i32x8 (&fbn)[2],
                                      f32x16 (&acc)[4][2]) {
  i32x8 fa[4];
#pragma unroll
  for (int i = 0; i < 4; ++i)
    fa[i] = ld2x16(Abuf + aoff + i * 2048, Abuf + ((aoff + i * 2048) ^ 16));
  if (LDB) {
    fbn[0] = ld2x16(Bnx, Bnx + 16);
    fbn[1] = ld2x16(Bnx + 2048, Bnx + 2048 + 16);
  }
  if (STG) {
    stgA(Xf, n0, kstage, Sbuf, tid);
    stgA(Xf, n0 + 128, kstage, Sbuf + 8192, tid);
  }
  __builtin_amdgcn_s_setprio(1);
#pragma unroll
  for (int i = 0; i < 4; ++i) acc[i][0] = mfma_mx(fa[i], fb[0], acc[i][0]);
#pragma unroll
  for (int i = 0; i < 4; ++i) acc[i][1] = mfma_mx(fa[i], fb[1], acc[i][1]);
  __builtin_amdgcn_s_setprio(0);
  if (VMC == 6) asm volatile("s_waitcnt vmcnt(6)" ::: "memory");
  else if (VMC == 4) asm volatile("s_waitcnt vmcnt(4)" ::: "memory");
  else if (VMC == 0) asm volatile("s_waitcnt vmcnt(0)" ::: "memory");
  if (BAR) BARRIER;
}

__global__ __launch_bounds__(512, 2)
void gemm_min_kernel(const unsigned char* __restrict__ Xf, const unsigned char* __restrict__ TfT,
                     const float* __restrict__ phi_b, unsigned* __restrict__ keys) {
  __shared__ __align__(16) unsigned char lds8[49152];   // 3 x 16KB A buffers

  const int tid = threadIdx.x;
  const int wave = tid >> 6, lane = tid & 63;
  const int wm = wave >> 2, wn = wave & 3;
  const int fr5 = lane & 31, h = lane >> 5;

  // 2D XCD chunking: 8 chunks of 8n x 16m tiles (~3MB working set / XCD L2)
  const int bid = blockIdx.x;
  const int xcd = bid & 7, idx = bid >> 3;
  const int nt = (xcd >> 1) * 8 + (idx >> 4);
  const int mt = (xcd & 1) * 16 + (idx & 15);
  const int n0 = nt * 256, m0 = mt * 256;

  // A fragment offset within a 16KB buffer (verified geometry from r10)
  const int key = (fr5 >> 1) & 3;
  const int aoff = (wm * 128 + fr5) * 64 + (((h << 1) ^ key) << 4);

  // B fragment base: fragment-major TfT[kt][row][64]; row = m0+wn*64+(j*32)+fr5
  const unsigned char* Bb = TfT + ((size_t)(m0 + wn * 64 + fr5)) * 64 + h * 32;
#define BK_T(kt) (Bb + (size_t)(kt) * (M_PTS * 64))

  unsigned char* B0 = lds8;
  unsigned char* B1 = lds8 + 16384;
  unsigned char* B2 = lds8 + 32768;

  // prologue: stage A tiles 0,1; drain; then load B frags of tile 0.
  stgA(Xf, n0, 0, B0, tid);       stgA(Xf, n0 + 128, 0, B0 + 8192, tid);
  stgA(Xf, n0, 64, B1, tid);      stgA(Xf, n0 + 128, 64, B1 + 8192, tid);
  asm volatile("s_waitcnt vmcnt(0)" ::: "memory");
  BARRIER;

  i32x8 fbA[2], fbB[2];
  fbA[0] = ld2x16(BK_T(0), BK_T(0) + 16);
  fbA[1] = ld2x16(BK_T(0) + 2048, BK_T(0) + 2048 + 16);

  f32x16 acc[4][2] = {};
  ktile<6, true, true, true>(B0, B2, Xf, BK_T(1), n0, 128, tid, aoff, fbA, fbB, acc);  // t0
  ktile<6, true, true, true>(B1, B0, Xf, BK_T(2), n0, 192, tid, aoff, fbB, fbA, acc);  // t1
  ktile<6, true, true, true>(B2, B1, Xf, BK_T(3), n0, 256, tid, aoff, fbA, fbB, acc);  // t2
  ktile<6, true, true, true>(B0, B2, Xf, BK_T(4), n0, 320, tid, aoff, fbB, fbA, acc);  // t3
  ktile<6, true, true, true>(B1, B0, Xf, BK_T(5), n0, 384, tid, aoff, fbA, fbB, acc);  // t4
  ktile<6, true, true, true>(B2, B1, Xf, BK_T(6), n0, 448, tid, aoff, fbB, fbA, acc);  // t5
  ktile<4, false, true, true>(B0, B2, Xf, BK_T(7), n0, 0, tid, aoff, fbA, fbB, acc);   // t6
  ktile<-1, false, false, false>(B1, B2, Xf, BK_T(7), n0, 0, tid, aoff, fbB, fbA, acc); // t7

  // Epilogue: v = phi_b[n] - dot; min over the wave's 128 rows per column.
  // 32x32 C/D layout (m74/m101): col = lane&31, row = (q&3)+8*(q>>2)+4*h
  float mv0 = 3.4e38f, mv1 = 3.4e38f;
#pragma unroll
  for (int i = 0; i < 4; ++i) {
    float pb[16];
#pragma unroll
    for (int q = 0; q < 16; ++q)
      pb[q] = phi_b[n0 + wm * 128 + i * 32 + (q & 3) + 8 * (q >> 2) + 4 * h];
#pragma unroll
    for (int q = 0; q < 16; ++q) {
      mv0 = fminf(mv0, pb[q] - acc[i][0][q]);
      mv1 = fminf(mv1, pb[q] - acc[i][1][q]);
    }
  }
  mv0 = fminf(mv0, __shfl_xor(mv0, 32));
  mv1 = fminf(mv1, __shfl_xor(mv1, 32));
  if (h == 0) {
    atomicMin(&keys[m0 + wn * 64 + fr5], fenc(mv0));
    atomicMin(&keys[m0 + wn * 64 + 32 + fr5], fenc(mv1));
  }
#undef BK_T
}

// =====================================================================
// Kernel 4: final reduce: mean(phi_k) + mean(phi_c). 1 block, 1024 thr.
// =====================================================================
__global__ __launch_bounds__(1024)
void finalize_kernel(const float* __restrict__ xsq, const float* __restrict__ phi_b,
                     const float* __restrict__ tsq, const unsigned* __restrict__ keys,
                     float* __restrict__ out) {
  const int t = threadIdx.x;
  double sk = 0.0, sc = 0.0;
  for (int n = t; n < N_PTS; n += 1024) sk += 0.5 * (double)xsq[n] - (double)phi_b[n];
  for (int m = t; m < M_PTS; m += 1024) sc += 0.5 * (double)tsq[m] + (double)fdec(keys[m]);
  const int lane = t & 63, wv = t >> 6;
#pragma unroll
  for (int m = 1; m <= 32; m <<= 1) {
    sk += __shfl_xor(sk, m);
    sc += __shfl_xor(sc, m);
  }
  __shared__ double pk[16], pc[16];
  if (lane == 0) { pk[wv] = sk; pc[wv] = sc; }
  __syncthreads();
  if (t == 0) {
    double a = 0.0, c = 0.0;
#pragma unroll
    for (int i = 0; i < 16; ++i) { a += pk[i]; c += pc[i]; }
    out[0] = (float)(a / N_PTS + c / M_PTS);
  }
}

// =====================================================================
extern "C" void kernel_launch(void* const* d_in, const int* in_sizes, int n_in,
                              void* d_out, int out_size, void* d_ws, size_t ws_size,
                              hipStream_t stream) {
  const float* x = (const float*)d_in[0];
  const float* tgt = (const float*)d_in[1];
  const float* W = (const float*)d_in[2];

  char* ws = (char*)d_ws;
  const size_t XB_BYTES = (size_t)N_PTS * DIM * 2;   // bf16 x (for phi_b)
  const size_t XF_BYTES = (size_t)N_PTS * DIM;       // fp8 x (plain row order)
  const size_t TF_BYTES = (size_t)M_PTS * DIM;       // fp8 t (fragment-major)
  const size_t WT_BYTES = (size_t)KDIM * DIM * 2;
  unsigned short* Xb = (unsigned short*)ws;
  unsigned char* Xf8 = (unsigned char*)(ws + XB_BYTES);
  unsigned char* TfT = (unsigned char*)(ws + XB_BYTES + XF_BYTES);
  unsigned short* WbT = (unsigned short*)(ws + XB_BYTES + XF_BYTES + TF_BYTES);
  float* phi_b = (float*)(ws + XB_BYTES + XF_BYTES + TF_BYTES + WT_BYTES);
  float* xsq = phi_b + N_PTS;
  float* tsq = xsq + N_PTS;
  unsigned* keys = (unsigned*)(tsq + M_PTS);

  const int prep_blocks = (N_PTS + M_PTS) / 4 + (KDIM * DIM) / 256;
  prep_all_kernel<<<prep_blocks, 256, 0, stream>>>(x, tgt, W, Xb, Xf8, TfT, WbT,
                                                   xsq, tsq, keys);
  phi_b_kernel<<<N_PTS / BT, 256, 0, stream>>>((const short*)Xb, (const short*)WbT, phi_b);
  gemm_min_kernel<<<(N_PTS / 256) * (M_PTS / 256), 512, 0, stream>>>(Xf8, TfT, phi_b, keys);
  finalize_kernel<<<1, 1024, 0, stream>>>(xsq, phi_b, tsq, keys, (float*)d_out);
}

// Round 12
// 69.566 us; speedup vs baseline: 1.5196x; 1.0317x over previous
//
#include <hip/hip_runtime.h>
#include <hip/hip_bf16.h>
#include <stdint.h>

typedef __attribute__((ext_vector_type(8))) short short8;
typedef __attribute__((ext_vector_type(4))) float f32x4;
typedef __attribute__((ext_vector_type(16))) float f32x16;
typedef __attribute__((ext_vector_type(4))) int i32x4;
typedef __attribute__((ext_vector_type(8))) int i32x8;

#define N_PTS 8192
#define M_PTS 8192
#define DIM   512
#define KDIM  128
#define BT    128   // phi_b tile
#define BKS   32

// ---- float <-> order-preserving uint key (for atomicMin on float) ----
__device__ __forceinline__ unsigned fenc(float f) {
  unsigned u = __float_as_uint(f);
  return (u & 0x80000000u) ? ~u : (u | 0x80000000u);
}
__device__ __forceinline__ float fdec(unsigned k) {
  unsigned u = (k & 0x80000000u) ? (k ^ 0x80000000u) : ~k;
  return __uint_as_float(u);
}

__device__ __forceinline__ unsigned short f2bf(float f) {
  union { __hip_bfloat16 h; unsigned short u; } c;
  c.h = __float2bfloat16(f);
  return c.u;
}

// ---- float -> OCP e4m3fn, RNE, flush |f|<2^-6 to 0 (x,t ~ N(0,1)) ----
__device__ __forceinline__ unsigned f2e4m3(float f) {
  unsigned u = __float_as_uint(f);
  unsigned s = (u >> 24) & 0x80;
  unsigned mag = u & 0x7fffffffu;
  unsigned r = mag + 0x0007ffffu + ((mag >> 20) & 1u);  // RNE to 3 mantissa bits
  int e = (int)(r >> 23) - 127;
  if (e < -6) return s;                                 // flush tiny to zero
  unsigned m = (r >> 20) & 7u;
  return s | (unsigned)((e + 7) << 3) | m;
}

// ---- async global -> LDS, 16B per lane ----
__device__ __forceinline__ void async_copy16(const void* g, void* l) {
  __builtin_amdgcn_global_load_lds(
      (const __attribute__((address_space(1))) void*)g,
      (__attribute__((address_space(3))) void*)l, 16, 0, 0);
}

// ---- bf16 LDS slot swizzle (phi_b kernel, verified 0 conflicts) ----
__device__ __forceinline__ int swz_slot(int row, int slot) {
  return slot ^ ((row >> 1) & 3);
}

// ---- A-tile chunk key: distinct quad permutation per 8-lane group ----
// depends only on row bits 1..4, so stage-side (r in 0..127) and
// read-side (fr5 + i*32 + wm*128) agree for every fragment block.
__device__ __forceinline__ int chunk_key(int row) {
  return ((row >> 1) & 3) ^ ((row >> 3) & 1) ^ (((row >> 4) & 1) << 1);
}

#define BARRIER __builtin_amdgcn_s_barrier()

// =====================================================================
// Kernel 1: prep-all. Blocks < 4096: one wave per row of x/target:
// x -> Xb(bf16) + Xf8(e4m3 plain rows) + xsq; target -> TfT (e4m3,
// FRAGMENT-MAJOR [kt][8192][64B]) + tsq + key init.
// Blocks >= 4096: W [D][K] fp32 -> WbT [K][D] bf16 transpose-cast.
// =====================================================================
__global__ __launch_bounds__(256)
void prep_all_kernel(const float* __restrict__ x, const float* __restrict__ tgt,
                     const float* __restrict__ W,
                     unsigned short* __restrict__ Xb, unsigned char* __restrict__ Xf8,
                     unsigned char* __restrict__ TfT, unsigned short* __restrict__ WbT,
                     float* __restrict__ xsq, float* __restrict__ tsq,
                     unsigned* __restrict__ keys) {
  const int bid = blockIdx.x;
  const int tid = threadIdx.x;
  if (bid >= (N_PTS + M_PTS) / 4) {
    const int o = (bid - (N_PTS + M_PTS) / 4) * 256 + tid;  // 0..65535
    const int k = o >> 9, d = o & 511;
    WbT[o] = f2bf(W[d * KDIM + k]);
    return;
  }
  const int gw = (bid * 256 + tid) >> 6;
  const int j = tid & 63;
  float s;
  if (gw < N_PTS) {
    const float* src = x + (size_t)gw * DIM + j * 8;
    float4 v0 = *(const float4*)src;
    float4 v1 = *(const float4*)(src + 4);
    s = v0.x * v0.x + v0.y * v0.y + v0.z * v0.z + v0.w * v0.w +
        v1.x * v1.x + v1.y * v1.y + v1.z * v1.z + v1.w * v1.w;
    unsigned short* db = Xb + (size_t)gw * DIM + j * 8;
    ushort4 ob0, ob1;
    ob0.x = f2bf(v0.x); ob0.y = f2bf(v0.y); ob0.z = f2bf(v0.z); ob0.w = f2bf(v0.w);
    ob1.x = f2bf(v1.x); ob1.y = f2bf(v1.y); ob1.z = f2bf(v1.z); ob1.w = f2bf(v1.w);
    *(ushort4*)db = ob0;
    *(ushort4*)(db + 4) = ob1;
    unsigned long long p = (unsigned long long)f2e4m3(v0.x)
        | ((unsigned long long)f2e4m3(v0.y) << 8)
        | ((unsigned long long)f2e4m3(v0.z) << 16)
        | ((unsigned long long)f2e4m3(v0.w) << 24)
        | ((unsigned long long)f2e4m3(v1.x) << 32)
        | ((unsigned long long)f2e4m3(v1.y) << 40)
        | ((unsigned long long)f2e4m3(v1.z) << 48)
        | ((unsigned long long)f2e4m3(v1.w) << 56);
    *(unsigned long long*)(Xf8 + (size_t)gw * DIM + j * 8) = p;
#pragma unroll
    for (int m = 1; m <= 32; m <<= 1) s += __shfl_xor(s, m);
    if (j == 0) xsq[gw] = s;
  } else {
    const int tr = gw - N_PTS;
    const float* src = tgt + (size_t)tr * DIM + j * 8;
    float4 v0 = *(const float4*)src;
    float4 v1 = *(const float4*)(src + 4);
    s = v0.x * v0.x + v0.y * v0.y + v0.z * v0.z + v0.w * v0.w +
        v1.x * v1.x + v1.y * v1.y + v1.z * v1.z + v1.w * v1.w;
    unsigned long long p = (unsigned long long)f2e4m3(v0.x)
        | ((unsigned long long)f2e4m3(v0.y) << 8)
        | ((unsigned long long)f2e4m3(v0.z) << 16)
        | ((unsigned long long)f2e4m3(v0.w) << 24)
        | ((unsigned long long)f2e4m3(v1.x) << 32)
        | ((unsigned long long)f2e4m3(v1.y) << 40)
        | ((unsigned long long)f2e4m3(v1.z) << 48)
        | ((unsigned long long)f2e4m3(v1.w) << 56);
    // fragment-major: [kt = j>>3][row tr][byte (j&7)*8]
    *(unsigned long long*)(TfT + ((size_t)(j >> 3) * M_PTS + tr) * 64 + (j & 7) * 8) = p;
#pragma unroll
    for (int m = 1; m <= 32; m <<= 1) s += __shfl_xor(s, m);
    if (j == 0) { tsq[tr] = s; keys[tr] = 0xFFFFFFFFu; }
  }
}

// =====================================================================
// Kernel 2: phi_b = logsumexp(Xb @ WbT^T) via bf16 MFMA (unchanged).
// =====================================================================
__global__ __launch_bounds__(256)
void phi_b_kernel(const short* __restrict__ Xb, const short* __restrict__ WbT,
                  float* __restrict__ phi_b) {
  __shared__ __align__(16) short As[BT * BKS];
  __shared__ __align__(16) short Bs[BT * BKS];
  __shared__ __align__(16) float lg[128][136];

  const int tid = threadIdx.x;
  const int wave = tid >> 6, lane = tid & 63;
  const int n0 = blockIdx.x * BT;
  const int srow = tid >> 2;
  const int sk8 = swz_slot(srow, tid & 3) * 8;
  const int wr = wave >> 1, wc = wave & 1;
  const int fr = lane & 15, g = lane >> 4;

  f32x4 acc[4][4] = {};
  for (int kt = 0; kt < DIM / BKS; ++kt) {
    const int k0 = kt * BKS;
    async_copy16(Xb + (size_t)(n0 + srow) * DIM + k0 + sk8, &As[wave * 512]);
    async_copy16(Xb + (size_t)(n0 + srow + 64) * DIM + k0 + sk8, &As[2048 + wave * 512]);
    async_copy16(WbT + (size_t)srow * DIM + k0 + sk8, &Bs[wave * 512]);
    async_copy16(WbT + (size_t)(srow + 64) * DIM + k0 + sk8, &Bs[2048 + wave * 512]);
    __syncthreads();
    short8 a[4], b[4];
#pragma unroll
    for (int i = 0; i < 4; ++i) {
      const int R = wr * 64 + i * 16 + fr;
      a[i] = *(const short8*)&As[R * BKS + swz_slot(R, g) * 8];
    }
#pragma unroll
    for (int j = 0; j < 4; ++j) {
      const int R = wc * 64 + j * 16 + fr;
      b[j] = *(const short8*)&Bs[R * BKS + swz_slot(R, g) * 8];
    }
#pragma unroll
    for (int i = 0; i < 4; ++i)
#pragma unroll
      for (int j = 0; j < 4; ++j)
        acc[i][j] = __builtin_amdgcn_mfma_f32_16x16x32_bf16(a[i], b[j], acc[i][j], 0, 0, 0);
    __syncthreads();
  }

  const int rq = g * 4;
#pragma unroll
  for (int i = 0; i < 4; ++i)
#pragma unroll
    for (int j = 0; j < 4; ++j)
#pragma unroll
      for (int q = 0; q < 4; ++q)
        lg[wr * 64 + i * 16 + rq + q][wc * 64 + j * 16 + fr] = acc[i][j][q];
  __syncthreads();

  const int row = tid >> 1, half = tid & 1;
  const float4* lr = (const float4*)(&lg[row][half * 64]);
  float mx = -3.4e38f;
#pragma unroll
  for (int c = 0; c < 16; ++c) {
    float4 v = lr[c];
    mx = fmaxf(mx, fmaxf(fmaxf(v.x, v.y), fmaxf(v.z, v.w)));
  }
  mx = fmaxf(mx, __shfl_xor(mx, 1));
  float s = 0.f;
#pragma unroll
  for (int c = 0; c < 16; ++c) {
    float4 v = lr[c];
    s += __expf(v.x - mx) + __expf(v.y - mx) + __expf(v.z - mx) + __expf(v.w - mx);
  }
  s += __shfl_xor(s, 1);
  if (half == 0) phi_b[n0 + row] = mx + logf(s);
}

// =====================================================================
// Kernel 3: fused MX-fp8 GEMM + min epilogue — B direct from L2,
// A staged in 3x16KB LDS, 1 barrier/K64 (structure proven r11).
// New: chunk_key with row bits 3-4 -> distinct quad perm per 8-lane
// group (A-read bank-conflict fix).
// =====================================================================
__device__ __forceinline__ void stgA(const unsigned char* __restrict__ mat,
                                     int rowbase, int kbyte,
                                     unsigned char* dst, int tid) {
  const int r = tid >> 2, d = tid & 3;
  async_copy16(mat + (size_t)(rowbase + r) * DIM + kbyte + ((d ^ chunk_key(r)) << 4),
               dst + (tid >> 6) * 1024);
}

__device__ __forceinline__ i32x8 ld2x16(const unsigned char* p0, const unsigned char* p1) {
  i32x4 lo = *(const i32x4*)p0;
  i32x4 hi = *(const i32x4*)p1;
  return __builtin_shufflevector(lo, hi, 0, 1, 2, 3, 4, 5, 6, 7);
}

__device__ __forceinline__ f32x16 mfma_mx(i32x8 a, i32x8 b, f32x16 c) {
  return __builtin_amdgcn_mfma_scale_f32_32x32x64_f8f6f4(a, b, c, 0, 0,
                                                         0, 0x7F, 0, 0x7F);
}

// VMC: vmcnt at tile end (6 steady, 4 = t6, -1 = none). STG: stage S(t+2).
// LDB: load fbn = B frags of tile t+1. BAR: trailing barrier.
template <int VMC, bool STG, bool LDB, bool BAR>
__device__ __forceinline__ void ktile(const unsigned char* Abuf, unsigned char* Sbuf,
                                      const unsigned char* __restrict__ Xf,
                                      const unsigned char* __restrict__ Bnx,
                                      int n0, int kstage, int tid, int aoff,
                                      i32x8 (&fb)[2], i32x8 (&fbn)[2],
                                      f32x16 (&acc)[4][2]) {
  i32x8 fa[4];
#pragma unroll
  for (int i = 0; i < 4; ++i)
    fa[i] = ld2x16(Abuf + aoff + i * 2048, Abuf + ((aoff + i * 2048) ^ 16));
  if (LDB) {
    fbn[0] = ld2x16(Bnx, Bnx + 16);
    fbn[1] = ld2x16(Bnx + 2048, Bnx + 2048 + 16);
  }
  if (STG) {
    stgA(Xf, n0, kstage, Sbuf, tid);
    stgA(Xf, n0 + 128, kstage, Sbuf + 8192, tid);
  }
  __builtin_amdgcn_s_setprio(1);
#pragma unroll
  for (int i = 0; i < 4; ++i) acc[i][0] = mfma_mx(fa[i], fb[0], acc[i][0]);
#pragma unroll
  for (int i = 0; i < 4; ++i) acc[i][1] = mfma_mx(fa[i], fb[1], acc[i][1]);
  __builtin_amdgcn_s_setprio(0);
  if (VMC == 6) asm volatile("s_waitcnt vmcnt(6)" ::: "memory");
  else if (VMC == 4) asm volatile("s_waitcnt vmcnt(4)" ::: "memory");
  else if (VMC == 0) asm volatile("s_waitcnt vmcnt(0)" ::: "memory");
  if (BAR) BARRIER;
}

__global__ __launch_bounds__(512, 2)
void gemm_min_kernel(const unsigned char* __restrict__ Xf, const unsigned char* __restrict__ TfT,
                     const float* __restrict__ phi_b, unsigned* __restrict__ keys) {
  __shared__ __align__(16) unsigned char lds8[49152];   // 3 x 16KB A buffers

  const int tid = threadIdx.x;
  const int wave = tid >> 6, lane = tid & 63;
  const int wm = wave >> 2, wn = wave & 3;
  const int fr5 = lane & 31, h = lane >> 5;

  // 2D XCD chunking: 8 chunks of 8n x 16m tiles (~3MB working set / XCD L2)
  const int bid = blockIdx.x;
  const int xcd = bid & 7, idx = bid >> 3;
  const int nt = (xcd >> 1) * 8 + (idx >> 4);
  const int mt = (xcd & 1) * 16 + (idx & 15);
  const int n0 = nt * 256, m0 = mt * 256;

  // A fragment offset: row*64 + ((2h ^ key(row))<<4); key uses row bits 1-4
  const int key = chunk_key(fr5);
  const int aoff = (wm * 128 + fr5) * 64 + (((h << 1) ^ key) << 4);

  // B fragment base: fragment-major TfT[kt][row][64]; row = m0+wn*64+(j*32)+fr5
  const unsigned char* Bb = TfT + ((size_t)(m0 + wn * 64 + fr5)) * 64 + h * 32;
#define BK_T(kt) (Bb + (size_t)(kt) * (M_PTS * 64))

  unsigned char* B0 = lds8;
  unsigned char* B1 = lds8 + 16384;
  unsigned char* B2 = lds8 + 32768;

  // prologue: stage A tiles 0,1; drain; then load B frags of tile 0.
  stgA(Xf, n0, 0, B0, tid);       stgA(Xf, n0 + 128, 0, B0 + 8192, tid);
  stgA(Xf, n0, 64, B1, tid);      stgA(Xf, n0 + 128, 64, B1 + 8192, tid);
  asm volatile("s_waitcnt vmcnt(0)" ::: "memory");
  BARRIER;

  i32x8 fbA[2], fbB[2];
  fbA[0] = ld2x16(BK_T(0), BK_T(0) + 16);
  fbA[1] = ld2x16(BK_T(0) + 2048, BK_T(0) + 2048 + 16);

  f32x16 acc[4][2] = {};
  ktile<6, true, true, true>(B0, B2, Xf, BK_T(1), n0, 128, tid, aoff, fbA, fbB, acc);  // t0
  ktile<6, true, true, true>(B1, B0, Xf, BK_T(2), n0, 192, tid, aoff, fbB, fbA, acc);  // t1
  ktile<6, true, true, true>(B2, B1, Xf, BK_T(3), n0, 256, tid, aoff, fbA, fbB, acc);  // t2
  ktile<6, true, true, true>(B0, B2, Xf, BK_T(4), n0, 320, tid, aoff, fbB, fbA, acc);  // t3
  ktile<6, true, true, true>(B1, B0, Xf, BK_T(5), n0, 384, tid, aoff, fbA, fbB, acc);  // t4
  ktile<6, true, true, true>(B2, B1, Xf, BK_T(6), n0, 448, tid, aoff, fbB, fbA, acc);  // t5
  ktile<4, false, true, true>(B0, B2, Xf, BK_T(7), n0, 0, tid, aoff, fbA, fbB, acc);   // t6
  ktile<-1, false, false, false>(B1, B2, Xf, BK_T(7), n0, 0, tid, aoff, fbB, fbA, acc); // t7

  // Epilogue: v = phi_b[n] - dot; min over the wave's 128 rows per column.
  // 32x32 C/D layout (m74/m101): col = lane&31, row = (q&3)+8*(q>>2)+4*h
  float mv0 = 3.4e38f, mv1 = 3.4e38f;
#pragma unroll
  for (int i = 0; i < 4; ++i) {
    float pb[16];
#pragma unroll
    for (int q = 0; q < 16; ++q)
      pb[q] = phi_b[n0 + wm * 128 + i * 32 + (q & 3) + 8 * (q >> 2) + 4 * h];
#pragma unroll
    for (int q = 0; q < 16; ++q) {
      mv0 = fminf(mv0, pb[q] - acc[i][0][q]);
      mv1 = fminf(mv1, pb[q] - acc[i][1][q]);
    }
  }
  mv0 = fminf(mv0, __shfl_xor(mv0, 32));
  mv1 = fminf(mv1, __shfl_xor(mv1, 32));
  if (h == 0) {
    atomicMin(&keys[m0 + wn * 64 + fr5], fenc(mv0));
    atomicMin(&keys[m0 + wn * 64 + 32 + fr5], fenc(mv1));
  }
#undef BK_T
}

// =====================================================================
// Kernel 4: partial reduce — 64 blocks x 256 threads, 1 elem/thread.
// Blocks 0-31: phi_k terms over n. Blocks 32-63: phi_c terms over m.
// Deterministic (fixed shuffle tree, fixed write slots).
// =====================================================================
__global__ __launch_bounds__(256)
void partial_kernel(const float* __restrict__ xsq, const float* __restrict__ phi_b,
                    const float* __restrict__ tsq, const unsigned* __restrict__ keys,
                    double* __restrict__ partials) {
  const int b = blockIdx.x, t = threadIdx.x;
  double s;
  if (b < 32) {
    const int n = b * 256 + t;
    s = 0.5 * (double)xsq[n] - (double)phi_b[n];
  } else {
    const int m = (b - 32) * 256 + t;
    s = 0.5 * (double)tsq[m] + (double)fdec(keys[m]);
  }
  const int lane = t & 63, wv = t >> 6;
#pragma unroll
  for (int k = 1; k <= 32; k <<= 1) s += __shfl_xor(s, k);
  __shared__ double ps[4];
  if (lane == 0) ps[wv] = s;
  __syncthreads();
  if (t == 0) partials[b] = ps[0] + ps[1] + ps[2] + ps[3];
}

// =====================================================================
// Kernel 5: final: sum 64 partials (fixed order), write scalar.
// =====================================================================
__global__ __launch_bounds__(64)
void final_kernel(const double* __restrict__ partials, float* __restrict__ out) {
  if (threadIdx.x == 0) {
    double a = 0.0, c = 0.0;
#pragma unroll
    for (int i = 0; i < 32; ++i) a += partials[i];
#pragma unroll
    for (int i = 32; i < 64; ++i) c += partials[i];
    out[0] = (float)(a / N_PTS + c / M_PTS);
  }
}

// =====================================================================
extern "C" void kernel_launch(void* const* d_in, const int* in_sizes, int n_in,
                              void* d_out, int out_size, void* d_ws, size_t ws_size,
                              hipStream_t stream) {
  const float* x = (const float*)d_in[0];
  const float* tgt = (const float*)d_in[1];
  const float* W = (const float*)d_in[2];

  char* ws = (char*)d_ws;
  const size_t XB_BYTES = (size_t)N_PTS * DIM * 2;   // bf16 x (for phi_b)
  const size_t XF_BYTES = (size_t)N_PTS * DIM;       // fp8 x (plain row order)
  const size_t TF_BYTES = (size_t)M_PTS * DIM;       // fp8 t (fragment-major)
  const size_t WT_BYTES = (size_t)KDIM * DIM * 2;
  unsigned short* Xb = (unsigned short*)ws;
  unsigned char* Xf8 = (unsigned char*)(ws + XB_BYTES);
  unsigned char* TfT = (unsigned char*)(ws + XB_BYTES + XF_BYTES);
  unsigned short* WbT = (unsigned short*)(ws + XB_BYTES + XF_BYTES + TF_BYTES);
  float* phi_b = (float*)(ws + XB_BYTES + XF_BYTES + TF_BYTES + WT_BYTES);
  float* xsq = phi_b + N_PTS;
  float* tsq = xsq + N_PTS;
  unsigned* keys = (unsigned*)(tsq + M_PTS);
  double* partials = (double*)(keys + M_PTS + 64);   // 8B-aligned region

  const int prep_blocks = (N_PTS + M_PTS) / 4 + (KDIM * DIM) / 256;
  prep_all_kernel<<<prep_blocks, 256, 0, stream>>>(x, tgt, W, Xb, Xf8, TfT, WbT,
                                                   xsq, tsq, keys);
  phi_b_kernel<<<N_PTS / BT, 256, 0, stream>>>((const short*)Xb, (const short*)WbT, phi_b);
  gemm_min_kernel<<<(N_PTS / 256) * (M_PTS / 256), 512, 0, stream>>>(Xf8, TfT, phi_b, keys);
  partial_kernel<<<64, 256, 0, stream>>>(xsq, phi_b, tsq, keys, partials);
  final_kernel<<<1, 64, 0, stream>>>(partials, (float*)d_out);
}